// Round 12
// baseline (335.721 us; speedup 1.0000x reference)
//
#include <hip/hip_runtime.h>

#define N0 4096
#define P1K 2048
#define P2K 1024

typedef short bf16x8 __attribute__((ext_vector_type(8)));
typedef float f32x4 __attribute__((ext_vector_type(4)));

__device__ __forceinline__ unsigned short f2bf(float f) {
  unsigned int u = __float_as_uint(f);
  unsigned int r = (u + 0x7fff + ((u >> 16) & 1)) >> 16;
  return (unsigned short)r;
}
__device__ __forceinline__ float bf2f(unsigned short h) {
  unsigned int u = ((unsigned int)h) << 16;
  return __uint_as_float(u);
}

// ---------------- helpers ----------------
__device__ __forceinline__ float blockReduceSum256(float v) {
  __shared__ float sh[16];
  int lane = threadIdx.x & 63;
  int w = threadIdx.x >> 6;
#pragma unroll
  for (int o = 32; o > 0; o >>= 1) v += __shfl_down(v, o, 64);
  __syncthreads();
  if (lane == 0) sh[w] = v;
  __syncthreads();
  float r = 0.f;
  if (threadIdx.x == 0) {
    int nw = (blockDim.x + 63) >> 6;
    for (int i = 0; i < nw; ++i) r += sh[i];
  }
  return r;  // valid on thread 0 only
}

__device__ __forceinline__ int blockScanExclusive(int v, volatile int* wsums) {
  int lane = threadIdx.x & 63, w = threadIdx.x >> 6;
  int x = v;
#pragma unroll
  for (int o = 1; o < 64; o <<= 1) {
    int y = __shfl_up(x, o, 64);
    if (lane >= o) x += y;
  }
  if (lane == 63) wsums[w] = x;
  __syncthreads();
  if (threadIdx.x < 64) {
    int nw = blockDim.x >> 6;
    int s = (threadIdx.x < nw) ? wsums[threadIdx.x] : 0;
#pragma unroll
    for (int o = 1; o < 16; o <<= 1) {
      int y = __shfl_up(s, o, 64);
      if (lane >= o) s += y;
    }
    if (threadIdx.x < nw) wsums[threadIdx.x] = s;
  }
  __syncthreads();
  int base = (w > 0) ? wsums[w - 1] : 0;
  __syncthreads();
  return base + x - v;
}

// ---------------- graph build bodies ----------------
__device__ __forceinline__ void count_edges_body(int b, const int* __restrict__ src,
                                                 const int* __restrict__ dst,
                                                 int* __restrict__ co, int* __restrict__ ci,
                                                 int E) {
  int e = b * 256 + threadIdx.x;
  if (e < E) {
    atomicAdd(&co[src[e]], 1);
    atomicAdd(&ci[dst[e]], 1);
  }
}

__device__ __forceinline__ void conv_body(int b, const float* __restrict__ t0,
                                          const float* __restrict__ t1,
                                          const float* __restrict__ t2,
                                          const float* __restrict__ t3,
                                          const float* __restrict__ t4,
                                          unsigned short* __restrict__ o0h,
                                          unsigned short* __restrict__ o0l,
                                          unsigned short* __restrict__ o1h,
                                          unsigned short* __restrict__ o1l,
                                          unsigned short* __restrict__ o2,
                                          unsigned short* __restrict__ o3,
                                          unsigned short* __restrict__ o4) {
  int idx = b * 256 + threadIdx.x;
  if (idx < 32768) {
    int k = idx >> 8, n = idx & 255;
    float v = t0[idx];
    unsigned short h = f2bf(v);
    o0h[(size_t)n * 128 + k] = h;
    o0l[(size_t)n * 128 + k] = f2bf(v - bf2f(h));
  } else if (idx < 163840) {
    int i = idx - 32768;
    int k = i >> 9, n = i & 511;
    float v = t1[i];
    unsigned short h = f2bf(v);
    o1h[(size_t)n * 256 + k] = h;
    o1l[(size_t)n * 256 + k] = f2bf(v - bf2f(h));
  } else if (idx < 425984) {
    int i = idx - 163840;
    int k = i >> 9, n = i & 511;
    o2[(size_t)n * 512 + k] = f2bf(t2[i]);
  } else if (idx < 557056) {
    int i = idx - 425984;
    int k = i >> 8, n = i & 255;
    o3[(size_t)n * 512 + k] = f2bf(t3[i]);
  } else if (idx < 589824) {
    int i = idx - 557056;
    int k = i >> 7, n = i & 127;
    o4[(size_t)n * 256 + k] = f2bf(t4[i]);
  }
}

__global__ __launch_bounds__(256) void fused_ce_conv(
    const int* __restrict__ src, const int* __restrict__ dst, int* __restrict__ co,
    int* __restrict__ ci, int E, const float* t0, const float* t1, const float* t2,
    const float* t3, const float* t4, unsigned short* o0h, unsigned short* o0l,
    unsigned short* o1h, unsigned short* o1l, unsigned short* o2, unsigned short* o3,
    unsigned short* o4) {
  if (blockIdx.x < 512) count_edges_body(blockIdx.x, src, dst, co, ci, E);
  else conv_body(blockIdx.x - 512, t0, t1, t2, t3, t4, o0h, o0l, o1h, o1l, o2, o3, o4);
}

// block 0: co->optr (+dinv0), block 1: ci->iptr
__global__ __launch_bounds__(1024) void exscan_dual(const int* __restrict__ co,
                                                    const int* __restrict__ ci,
                                                    int* __restrict__ optr,
                                                    int* __restrict__ iptr,
                                                    float* __restrict__ dinv0) {
  __shared__ int ls[1024];
  const int* cnt = blockIdx.x ? ci : co;
  int* ptr = blockIdx.x ? iptr : optr;
  int t = threadIdx.x;
  int v0 = cnt[t * 4], v1 = cnt[t * 4 + 1], v2 = cnt[t * 4 + 2], v3 = cnt[t * 4 + 3];
  int s = v0 + v1 + v2 + v3;
  ls[t] = s;
  __syncthreads();
  for (int off = 1; off < 1024; off <<= 1) {
    int x = (t >= off) ? ls[t - off] : 0;
    __syncthreads();
    ls[t] += x;
    __syncthreads();
  }
  int ex = (t > 0) ? ls[t - 1] : 0;
  ptr[t * 4]     = ex;
  ptr[t * 4 + 1] = ex + v0;
  ptr[t * 4 + 2] = ex + v0 + v1;
  ptr[t * 4 + 3] = ex + v0 + v1 + v2;
  if (t == 1023) ptr[4096] = ex + s;
  if (blockIdx.x == 0) {
    dinv0[t * 4]     = rsqrtf((float)v0 + 1.f);
    dinv0[t * 4 + 1] = rsqrtf((float)v1 + 1.f);
    dinv0[t * 4 + 2] = rsqrtf((float)v2 + 1.f);
    dinv0[t * 4 + 3] = rsqrtf((float)v3 + 1.f);
  }
}

__device__ __forceinline__ void fill_body(int b, const int* __restrict__ src,
                                          const int* __restrict__ dst,
                                          const int* __restrict__ optr,
                                          const int* __restrict__ iptr,
                                          int* __restrict__ fo, int* __restrict__ fi,
                                          int* __restrict__ odst, int* __restrict__ isrc,
                                          int E) {
  int e = b * 256 + threadIdx.x;
  if (e < E) {
    int s = src[e], d = dst[e];
    odst[optr[s] + atomicAdd(&fo[s], 1)] = d;
    isrc[iptr[d] + atomicAdd(&fi[d], 1)] = s;
  }
}

// ---- fp32-emulated MFMA GEMM (3-term bf16 split) body; smem: 32768 B ----
template <bool TOUT>
__device__ void gemm3_body(char* smem, int bid, const float* __restrict__ A,
                           const unsigned short* __restrict__ BhT,
                           const unsigned short* __restrict__ BlT,
                           const int* __restrict__ permA, const float* __restrict__ valsA,
                           const float* __restrict__ dinv, float* __restrict__ C,
                           unsigned short* __restrict__ ChT, unsigned short* __restrict__ ClT,
                           int M, int N, int K, int nbx) {
  unsigned short* U = (unsigned short*)smem;
  unsigned short* Ah = U;
  unsigned short* Al = U + 4096;
  unsigned short* Bh = U + 8192;
  unsigned short* Bl = U + 12288;
  int tid = threadIdx.x;
  int by = bid / nbx, bx = bid % nbx;
  int row0 = by << 6, col0 = bx << 6;
  int l = tid & 63, wv = tid >> 6;
  int wr = (wv >> 1) << 5, wc = (wv & 1) << 5;
  f32x4 acc[2][2] = {};
  for (int k0 = 0; k0 < K; k0 += 64) {
#pragma unroll
    for (int it = 0; it < 2; ++it) {
      int idx = (it << 8) + tid;
      int r = idx >> 3, c8 = idx & 7;
      int sw = c8 ^ (r & 7);
      int row = row0 + r;
      int srow = permA ? permA[row] : row;
      float vs = valsA ? valsA[row] : 1.f;
      const float* Af = A + (size_t)srow * K + k0 + (c8 << 3);
      float4 f0 = *(const float4*)Af;
      float4 f1 = *(const float4*)(Af + 4);
      float vv[8] = {f0.x * vs, f0.y * vs, f0.z * vs, f0.w * vs,
                     f1.x * vs, f1.y * vs, f1.z * vs, f1.w * vs};
      uint4 uh, ul;
      unsigned short hh[8], ll[8];
#pragma unroll
      for (int q = 0; q < 8; ++q) {
        hh[q] = f2bf(vv[q]);
        ll[q] = f2bf(vv[q] - bf2f(hh[q]));
      }
      uh.x = (unsigned)hh[0] | ((unsigned)hh[1] << 16);
      uh.y = (unsigned)hh[2] | ((unsigned)hh[3] << 16);
      uh.z = (unsigned)hh[4] | ((unsigned)hh[5] << 16);
      uh.w = (unsigned)hh[6] | ((unsigned)hh[7] << 16);
      ul.x = (unsigned)ll[0] | ((unsigned)ll[1] << 16);
      ul.y = (unsigned)ll[2] | ((unsigned)ll[3] << 16);
      ul.z = (unsigned)ll[4] | ((unsigned)ll[5] << 16);
      ul.w = (unsigned)ll[6] | ((unsigned)ll[7] << 16);
      ((uint4*)Ah)[(r << 3) + sw] = uh;
      ((uint4*)Al)[(r << 3) + sw] = ul;
      ((uint4*)Bh)[(r << 3) + sw] =
          *(const uint4*)(BhT + (size_t)(col0 + r) * K + k0 + (c8 << 3));
      ((uint4*)Bl)[(r << 3) + sw] =
          *(const uint4*)(BlT + (size_t)(col0 + r) * K + k0 + (c8 << 3));
    }
    __syncthreads();
#pragma unroll
    for (int kk2 = 0; kk2 < 2; ++kk2) {
      int ch = (kk2 << 2) + (l >> 4);
      int ra = wr + (l & 15), rb = ra + 16;
      int ca = wc + (l & 15), cb = ca + 16;
      int oa0 = (ra << 6) + ((ch ^ (ra & 7)) << 3);
      int oa1 = (rb << 6) + ((ch ^ (rb & 7)) << 3);
      int ob0 = (ca << 6) + ((ch ^ (ca & 7)) << 3);
      int ob1 = (cb << 6) + ((ch ^ (cb & 7)) << 3);
      bf16x8 ah0 = *(const bf16x8*)&Ah[oa0], ah1 = *(const bf16x8*)&Ah[oa1];
      bf16x8 al0 = *(const bf16x8*)&Al[oa0], al1 = *(const bf16x8*)&Al[oa1];
      bf16x8 bh0 = *(const bf16x8*)&Bh[ob0], bh1 = *(const bf16x8*)&Bh[ob1];
      bf16x8 bl0 = *(const bf16x8*)&Bl[ob0], bl1 = *(const bf16x8*)&Bl[ob1];
      acc[0][0] = __builtin_amdgcn_mfma_f32_16x16x32_bf16(ah0, bh0, acc[0][0], 0, 0, 0);
      acc[0][1] = __builtin_amdgcn_mfma_f32_16x16x32_bf16(ah0, bh1, acc[0][1], 0, 0, 0);
      acc[1][0] = __builtin_amdgcn_mfma_f32_16x16x32_bf16(ah1, bh0, acc[1][0], 0, 0, 0);
      acc[1][1] = __builtin_amdgcn_mfma_f32_16x16x32_bf16(ah1, bh1, acc[1][1], 0, 0, 0);
      acc[0][0] = __builtin_amdgcn_mfma_f32_16x16x32_bf16(ah0, bl0, acc[0][0], 0, 0, 0);
      acc[0][1] = __builtin_amdgcn_mfma_f32_16x16x32_bf16(ah0, bl1, acc[0][1], 0, 0, 0);
      acc[1][0] = __builtin_amdgcn_mfma_f32_16x16x32_bf16(ah1, bl0, acc[1][0], 0, 0, 0);
      acc[1][1] = __builtin_amdgcn_mfma_f32_16x16x32_bf16(ah1, bl1, acc[1][1], 0, 0, 0);
      acc[0][0] = __builtin_amdgcn_mfma_f32_16x16x32_bf16(al0, bh0, acc[0][0], 0, 0, 0);
      acc[0][1] = __builtin_amdgcn_mfma_f32_16x16x32_bf16(al0, bh1, acc[0][1], 0, 0, 0);
      acc[1][0] = __builtin_amdgcn_mfma_f32_16x16x32_bf16(al1, bh0, acc[1][0], 0, 0, 0);
      acc[1][1] = __builtin_amdgcn_mfma_f32_16x16x32_bf16(al1, bh1, acc[1][1], 0, 0, 0);
    }
    __syncthreads();
  }
  int lrow = (l >> 4) << 2, lcol = l & 15;
  float* tf = (float*)smem;
#pragma unroll
  for (int i = 0; i < 2; ++i)
#pragma unroll
    for (int j = 0; j < 2; ++j) {
      int lc = wc + (j << 4) + lcol;
      int lr0 = wr + (i << 4) + lrow;
      int c = col0 + lc;
#pragma unroll
      for (int rg = 0; rg < 4; ++rg) {
        int lr = lr0 + rg;
        int r = row0 + lr;
        float dv = dinv ? dinv[r] : 1.f;
        float v = acc[i][j][rg] * dv;
        if (C) C[(size_t)r * N + c] = v;
        if (TOUT) tf[lr * 65 + lc] = v;
      }
    }
  if (TOUT) {
    __syncthreads();
    for (int it = 0; it < 16; ++it) {
      int idx = (it << 8) + tid;
      int rr = idx >> 6, cc = idx & 63;
      float v = tf[cc * 65 + rr];
      unsigned short h = f2bf(v);
      size_t o = (size_t)(col0 + rr) * M + row0 + cc;
      ChT[o] = h;
      ClT[o] = f2bf(v - bf2f(h));
    }
  }
}

__global__ __launch_bounds__(256) void fused_fill_g3(
    const int* src, const int* dst, const int* optr, const int* iptr, int* fo, int* fi,
    int* odst, int* isrc, int E, const float* x, const unsigned short* t0hT,
    const unsigned short* t0lT, const float* dinv0, float* SA) {
  __shared__ char smem[32768];
  if (blockIdx.x < 512) fill_body(blockIdx.x, src, dst, optr, iptr, fo, fi, odst, isrc, E);
  else gemm3_body<false>(smem, blockIdx.x - 512, x, t0hT, t0lT, nullptr, nullptr, dinv0,
                         SA, nullptr, nullptr, 4096, 256, 128, 4);
}

// ---- 64x64-tile bf16 transpose body ----
__device__ void transpose_body(char* smem, int bid, const unsigned short* __restrict__ in,
                               unsigned short* __restrict__ out, int n) {
  unsigned short* t = (unsigned short*)smem;  // [64][65]
  int nb = n >> 6;
  int bx = bid % nb, by = bid / nb;
  int r0 = by << 6, c0 = bx << 6;
  for (int it = 0; it < 16; ++it) {
    int idx = (it << 8) + threadIdx.x;
    int r = idx >> 6, c = idx & 63;
    t[r * 65 + c] = in[(size_t)(r0 + r) * n + c0 + c];
  }
  __syncthreads();
  for (int it = 0; it < 16; ++it) {
    int idx = (it << 8) + threadIdx.x;
    int r = idx >> 6, c = idx & 63;
    out[(size_t)(c0 + r) * n + r0 + c] = t[c * 65 + r];
  }
}

__global__ __launch_bounds__(256) void fused_tr_g3(
    const unsigned short* W1b, unsigned short* W1bT, const float* x0,
    const unsigned short* t1hT, const unsigned short* t1lT, const int* perm1,
    const float* vals1, const float* dinv1, unsigned short* ZhT, unsigned short* ZlT) {
  __shared__ char smem[32768];
  if (blockIdx.x < 1024) transpose_body(smem, blockIdx.x, W1b, W1bT, 2048);
  else gemm3_body<true>(smem, blockIdx.x - 1024, x0, t1hT, t1lT, perm1, vals1, dinv1,
                        nullptr, ZhT, ZlT, 2048, 512, 256, 8);
}

// ---- dual-B split-K GEMM: Pf[s] = A @ (Bh + Bl); compile-time SPL ----
template <int SPL>
__global__ __launch_bounds__(256) void gemm_skd(const unsigned short* __restrict__ A,
                                                const unsigned short* __restrict__ BhT,
                                                const unsigned short* __restrict__ BlT,
                                                float* __restrict__ Pf,
                                                int M, int N, int K, int nbx, int nb2d) {
  __shared__ unsigned short As[4096], Bh[4096], Bl[4096];
  int tid = threadIdx.x;
  int s = blockIdx.x / nb2d;
  int r2 = blockIdx.x % nb2d;
  int by = r2 / nbx, bx = r2 % nbx;
  int row0 = by << 6, col0 = bx << 6;
  int kc = K / SPL;
  int ks = s * kc, ke = ks + kc;
  int l = tid & 63, wv = tid >> 6;
  int wr = (wv >> 1) << 5, wc = (wv & 1) << 5;
  f32x4 acc[2][2] = {};
  for (int k0 = ks; k0 < ke; k0 += 64) {
#pragma unroll
    for (int it = 0; it < 2; ++it) {
      int idx = (it << 8) + tid;
      int r = idx >> 3, c8 = idx & 7;
      int sw = c8 ^ (r & 7);
      ((uint4*)As)[(r << 3) + sw] =
          *(const uint4*)(A + (size_t)(row0 + r) * K + k0 + (c8 << 3));
      ((uint4*)Bh)[(r << 3) + sw] =
          *(const uint4*)(BhT + (size_t)(col0 + r) * K + k0 + (c8 << 3));
      ((uint4*)Bl)[(r << 3) + sw] =
          *(const uint4*)(BlT + (size_t)(col0 + r) * K + k0 + (c8 << 3));
    }
    __syncthreads();
#pragma unroll
    for (int kk2 = 0; kk2 < 2; ++kk2) {
      int ch = (kk2 << 2) + (l >> 4);
      int ra = wr + (l & 15), rb = ra + 16;
      int ca = wc + (l & 15), cb = ca + 16;
      bf16x8 a0 = *(const bf16x8*)&As[(ra << 6) + ((ch ^ (ra & 7)) << 3)];
      bf16x8 a1 = *(const bf16x8*)&As[(rb << 6) + ((ch ^ (rb & 7)) << 3)];
      bf16x8 bh0 = *(const bf16x8*)&Bh[(ca << 6) + ((ch ^ (ca & 7)) << 3)];
      bf16x8 bh1 = *(const bf16x8*)&Bh[(cb << 6) + ((ch ^ (cb & 7)) << 3)];
      bf16x8 bl0 = *(const bf16x8*)&Bl[(ca << 6) + ((ch ^ (ca & 7)) << 3)];
      bf16x8 bl1 = *(const bf16x8*)&Bl[(cb << 6) + ((ch ^ (cb & 7)) << 3)];
      acc[0][0] = __builtin_amdgcn_mfma_f32_16x16x32_bf16(a0, bh0, acc[0][0], 0, 0, 0);
      acc[0][1] = __builtin_amdgcn_mfma_f32_16x16x32_bf16(a0, bh1, acc[0][1], 0, 0, 0);
      acc[1][0] = __builtin_amdgcn_mfma_f32_16x16x32_bf16(a1, bh0, acc[1][0], 0, 0, 0);
      acc[1][1] = __builtin_amdgcn_mfma_f32_16x16x32_bf16(a1, bh1, acc[1][1], 0, 0, 0);
      acc[0][0] = __builtin_amdgcn_mfma_f32_16x16x32_bf16(a0, bl0, acc[0][0], 0, 0, 0);
      acc[0][1] = __builtin_amdgcn_mfma_f32_16x16x32_bf16(a0, bl1, acc[0][1], 0, 0, 0);
      acc[1][0] = __builtin_amdgcn_mfma_f32_16x16x32_bf16(a1, bl0, acc[1][0], 0, 0, 0);
      acc[1][1] = __builtin_amdgcn_mfma_f32_16x16x32_bf16(a1, bl1, acc[1][1], 0, 0, 0);
    }
    __syncthreads();
  }
  int lrow = (l >> 4) << 2, lcol = l & 15;
  float* P = Pf + (size_t)s * M * N;
#pragma unroll
  for (int i = 0; i < 2; ++i)
#pragma unroll
    for (int j = 0; j < 2; ++j) {
      int c = col0 + wc + (j << 4) + lcol;
      int r0 = row0 + wr + (i << 4) + lrow;
#pragma unroll
      for (int rg = 0; rg < 4; ++rg)
        P[(size_t)(r0 + rg) * N + c] = acc[i][j][rg];
    }
}

// ---- split-K bf16 MFMA GEMM (A bf16); compile-time SPL ----
template <int SPL>
__global__ __launch_bounds__(256) void gemm_sk(const unsigned short* __restrict__ A,
                                               const unsigned short* __restrict__ BT,
                                               float* __restrict__ Pf,
                                               int M, int N, int K, int nbx, int nb2d) {
  __shared__ unsigned short As[4096];
  __shared__ unsigned short Bs[4096];
  int tid = threadIdx.x;
  int s = blockIdx.x / nb2d;
  int r2 = blockIdx.x % nb2d;
  int by = r2 / nbx, bx = r2 % nbx;
  int row0 = by << 6, col0 = bx << 6;
  int kc = K / SPL;
  int ks = s * kc, ke = ks + kc;
  int l = tid & 63, wv = tid >> 6;
  int wr = (wv >> 1) << 5, wc = (wv & 1) << 5;
  f32x4 acc[2][2] = {};
  for (int k0 = ks; k0 < ke; k0 += 64) {
#pragma unroll
    for (int it = 0; it < 2; ++it) {
      int idx = (it << 8) + tid;
      int r = idx >> 3, c8 = idx & 7;
      int sw = c8 ^ (r & 7);
      ((uint4*)As)[(r << 3) + sw] =
          *(const uint4*)(A + (size_t)(row0 + r) * K + k0 + (c8 << 3));
      ((uint4*)Bs)[(r << 3) + sw] =
          *(const uint4*)(BT + (size_t)(col0 + r) * K + k0 + (c8 << 3));
    }
    __syncthreads();
#pragma unroll
    for (int kk2 = 0; kk2 < 2; ++kk2) {
      int ch = (kk2 << 2) + (l >> 4);
      int ra = wr + (l & 15), rb = ra + 16;
      int ca = wc + (l & 15), cb = ca + 16;
      bf16x8 a0 = *(const bf16x8*)&As[(ra << 6) + ((ch ^ (ra & 7)) << 3)];
      bf16x8 a1 = *(const bf16x8*)&As[(rb << 6) + ((ch ^ (rb & 7)) << 3)];
      bf16x8 b0 = *(const bf16x8*)&Bs[(ca << 6) + ((ch ^ (ca & 7)) << 3)];
      bf16x8 b1 = *(const bf16x8*)&Bs[(cb << 6) + ((ch ^ (cb & 7)) << 3)];
      acc[0][0] = __builtin_amdgcn_mfma_f32_16x16x32_bf16(a0, b0, acc[0][0], 0, 0, 0);
      acc[0][1] = __builtin_amdgcn_mfma_f32_16x16x32_bf16(a0, b1, acc[0][1], 0, 0, 0);
      acc[1][0] = __builtin_amdgcn_mfma_f32_16x16x32_bf16(a1, b0, acc[1][0], 0, 0, 0);
      acc[1][1] = __builtin_amdgcn_mfma_f32_16x16x32_bf16(a1, b1, acc[1][1], 0, 0, 0);
    }
    __syncthreads();
  }
  int lrow = (l >> 4) << 2, lcol = l & 15;
  float* P = Pf + (size_t)s * M * N;
#pragma unroll
  for (int i = 0; i < 2; ++i)
#pragma unroll
    for (int j = 0; j < 2; ++j) {
      int c = col0 + wc + (j << 4) + lcol;
      int r0 = row0 + wr + (i << 4) + lrow;
#pragma unroll
      for (int rg = 0; rg < 4; ++rg)
        P[(size_t)(r0 + rg) * N + c] = acc[i][j][rg];
    }
}

// ---- non-split GEMM with fused epilogue; smem: 16640 B ----
__device__ void gemm_e_body(char* smem, int bid, const float* __restrict__ A,
                            const unsigned short* __restrict__ BT,
                            const int* __restrict__ permA, const float* __restrict__ valsA,
                            const float* __restrict__ dinv, int dm,
                            float* __restrict__ Cf, unsigned short* __restrict__ CbT,
                            int M, int N, int K, int nbx) {
  unsigned short* As = (unsigned short*)smem;
  unsigned short* Bs = (unsigned short*)(smem + 8192);
  int tid = threadIdx.x;
  int by = bid / nbx, bx = bid % nbx;
  int row0 = by << 6, col0 = bx << 6;
  int l = tid & 63, wv = tid >> 6;
  int wr = (wv >> 1) << 5, wc = (wv & 1) << 5;
  f32x4 acc[2][2] = {};
  for (int k0 = 0; k0 < K; k0 += 64) {
#pragma unroll
    for (int it = 0; it < 2; ++it) {
      int idx = (it << 8) + tid;
      int r = idx >> 3, c8 = idx & 7;
      int sw = c8 ^ (r & 7);
      int row = row0 + r;
      int srow = permA ? permA[row] : row;
      float vs = valsA ? valsA[row] : 1.f;
      const float* Af = A + (size_t)srow * K + k0 + (c8 << 3);
      float4 f0 = *(const float4*)Af;
      float4 f1 = *(const float4*)(Af + 4);
      uint4 u;
      u.x = (unsigned)f2bf(f0.x * vs) | ((unsigned)f2bf(f0.y * vs) << 16);
      u.y = (unsigned)f2bf(f0.z * vs) | ((unsigned)f2bf(f0.w * vs) << 16);
      u.z = (unsigned)f2bf(f1.x * vs) | ((unsigned)f2bf(f1.y * vs) << 16);
      u.w = (unsigned)f2bf(f1.z * vs) | ((unsigned)f2bf(f1.w * vs) << 16);
      ((uint4*)As)[(r << 3) + sw] = u;
      ((uint4*)Bs)[(r << 3) + sw] =
          *(const uint4*)(BT + (size_t)(col0 + r) * K + k0 + (c8 << 3));
    }
    __syncthreads();
#pragma unroll
    for (int kk2 = 0; kk2 < 2; ++kk2) {
      int ch = (kk2 << 2) + (l >> 4);
      int ra = wr + (l & 15), rb = ra + 16;
      int ca = wc + (l & 15), cb = ca + 16;
      bf16x8 a0 = *(const bf16x8*)&As[(ra << 6) + ((ch ^ (ra & 7)) << 3)];
      bf16x8 a1 = *(const bf16x8*)&As[(rb << 6) + ((ch ^ (rb & 7)) << 3)];
      bf16x8 b0 = *(const bf16x8*)&Bs[(ca << 6) + ((ch ^ (ca & 7)) << 3)];
      bf16x8 b1 = *(const bf16x8*)&Bs[(cb << 6) + ((ch ^ (cb & 7)) << 3)];
      acc[0][0] = __builtin_amdgcn_mfma_f32_16x16x32_bf16(a0, b0, acc[0][0], 0, 0, 0);
      acc[0][1] = __builtin_amdgcn_mfma_f32_16x16x32_bf16(a0, b1, acc[0][1], 0, 0, 0);
      acc[1][0] = __builtin_amdgcn_mfma_f32_16x16x32_bf16(a1, b0, acc[1][0], 0, 0, 0);
      acc[1][1] = __builtin_amdgcn_mfma_f32_16x16x32_bf16(a1, b1, acc[1][1], 0, 0, 0);
    }
    __syncthreads();
  }
  int lrow = (l >> 4) << 2, lcol = l & 15;
  float* tf = (float*)smem;
#pragma unroll
  for (int i = 0; i < 2; ++i)
#pragma unroll
    for (int j = 0; j < 2; ++j) {
      int lc = wc + (j << 4) + lcol;
      int lr0 = wr + (i << 4) + lrow;
      int c = col0 + lc;
#pragma unroll
      for (int rg = 0; rg < 4; ++rg) {
        int lr = lr0 + rg;
        int r = row0 + lr;
        float dv = (dm == 1) ? dinv[r] : 1.f;
        float v = acc[i][j][rg] * dv;
        if (Cf) Cf[(size_t)r * N + c] = v;
        if (CbT) tf[lr * 65 + lc] = v;
      }
    }
  if (CbT) {
    __syncthreads();
    for (int it = 0; it < 16; ++it) {
      int idx = (it << 8) + tid;
      int rr = idx >> 6, cc = idx & 63;
      CbT[(size_t)(col0 + rr) * M + row0 + cc] = f2bf(tf[cc * 65 + rr]);
    }
  }
}

__global__ __launch_bounds__(256) void gemm_e_k(const float* A, const unsigned short* BT,
                                                const int* permA, const float* valsA,
                                                const float* dinv, int dm, float* Cf,
                                                unsigned short* CbT, int M, int N, int K,
                                                int nbx) {
  __shared__ char smem[16640];
  gemm_e_body(smem, blockIdx.x, A, BT, permA, valsA, dinv, dm, Cf, CbT, M, N, K, nbx);
}

// ---- W2f += A1[p2,:]@A1[:,p2] split-K 8 + row-sum atomics; smem: 16896 B ----
__device__ void mm_w2_body(char* smem, int bid, const unsigned short* __restrict__ Wb,
                           const unsigned short* __restrict__ WbT,
                           const int* __restrict__ perm2, float* __restrict__ W2f,
                           float* __restrict__ degsum2) {
  unsigned short* As = (unsigned short*)smem;
  unsigned short* Bs = (unsigned short*)(smem + 8192);
  int* pr = (int*)(smem + 16384);
  int* pc = pr + 64;
  int tid = threadIdx.x;
  int s = bid >> 8;          // 0..7
  int t2d = bid & 255;
  int bx = t2d & 15, by = t2d >> 4;
  int row0 = by << 6, col0 = bx << 6;
  int ks = s * 256, ke = ks + 256;
  if (tid < 64) pr[tid] = perm2[row0 + tid];
  else if (tid < 128) pc[tid - 64] = perm2[col0 + tid - 128 + 64];
  __syncthreads();
  int l = tid & 63, wv = tid >> 6;
  int wr = (wv >> 1) << 5, wc = (wv & 1) << 5;
  f32x4 acc[2][2] = {};
  for (int k0 = ks; k0 < ke; k0 += 64) {
#pragma unroll
    for (int it = 0; it < 2; ++it) {
      int idx = (it << 8) + tid;
      int r = idx >> 3, c8 = idx & 7;
      int sw = c8 ^ (r & 7);
      ((uint4*)As)[(r << 3) + sw] =
          *(const uint4*)(Wb + (size_t)pr[r] * 2048 + k0 + (c8 << 3));
      ((uint4*)Bs)[(r << 3) + sw] =
          *(const uint4*)(WbT + (size_t)pc[r] * 2048 + k0 + (c8 << 3));
    }
    __syncthreads();
#pragma unroll
    for (int kk2 = 0; kk2 < 2; ++kk2) {
      int ch = (kk2 << 2) + (l >> 4);
      int ra = wr + (l & 15), rb = ra + 16;
      int ca = wc + (l & 15), cb = ca + 16;
      bf16x8 a0 = *(const bf16x8*)&As[(ra << 6) + ((ch ^ (ra & 7)) << 3)];
      bf16x8 a1 = *(const bf16x8*)&As[(rb << 6) + ((ch ^ (rb & 7)) << 3)];
      bf16x8 b0 = *(const bf16x8*)&Bs[(ca << 6) + ((ch ^ (ca & 7)) << 3)];
      bf16x8 b1 = *(const bf16x8*)&Bs[(cb << 6) + ((ch ^ (cb & 7)) << 3)];
      acc[0][0] = __builtin_amdgcn_mfma_f32_16x16x32_bf16(a0, b0, acc[0][0], 0, 0, 0);
      acc[0][1] = __builtin_amdgcn_mfma_f32_16x16x32_bf16(a0, b1, acc[0][1], 0, 0, 0);
      acc[1][0] = __builtin_amdgcn_mfma_f32_16x16x32_bf16(a1, b0, acc[1][0], 0, 0, 0);
      acc[1][1] = __builtin_amdgcn_mfma_f32_16x16x32_bf16(a1, b1, acc[1][1], 0, 0, 0);
    }
    __syncthreads();
  }
  int lrow = (l >> 4) << 2, lcol = l & 15;
#pragma unroll
  for (int i = 0; i < 2; ++i)
#pragma unroll
    for (int j = 0; j < 2; ++j) {
      int c = col0 + wc + (j << 4) + lcol;
      int r0 = row0 + wr + (i << 4) + lrow;
#pragma unroll
      for (int rg = 0; rg < 4; ++rg)
        atomicAdd(&W2f[(size_t)(r0 + rg) * 1024 + c], acc[i][j][rg]);
    }
#pragma unroll
  for (int i = 0; i < 2; ++i)
#pragma unroll
    for (int rg = 0; rg < 4; ++rg) {
      float rs = acc[i][0][rg] + acc[i][1][rg];
#pragma unroll
      for (int o = 1; o < 16; o <<= 1) rs += __shfl_xor(rs, o, 64);
      if ((l & 15) == 0) {
        int r = row0 + wr + (i << 4) + lrow + rg;
        atomicAdd(&degsum2[r], rs);
      }
    }
}

__global__ __launch_bounds__(256) void fused_w2_g2a(
    const unsigned short* Wb, const unsigned short* WbT, const int* perm2, float* W2f,
    float* degsum2, const float* x1b, const unsigned short* t2T, const float* vals2,
    unsigned short* SAbT) {
  __shared__ char smem[16896];
  if (blockIdx.x < 2048) mm_w2_body(smem, blockIdx.x, Wb, WbT, perm2, W2f, degsum2);
  else gemm_e_body(smem, blockIdx.x - 2048, x1b, t2T, perm2, vals2, nullptr, 0,
                   nullptr, SAbT, 1024, 512, 512, 8);
}

// W2f -> W2Tb = ((W2 diag-zeroed + I) rows scaled by dinv2)^T bf16; emit dinv2
__global__ __launch_bounds__(256) void w2T(const float* __restrict__ W2f,
                                           const float* __restrict__ degsum2,
                                           unsigned short* __restrict__ W2Tb,
                                           float* __restrict__ dinv2v) {
  __shared__ float t[64][65];
  __shared__ float ds[64];
  int bx = blockIdx.x & 15, by = blockIdx.x >> 4;
  int r0 = by << 6, c0 = bx << 6;
  if (threadIdx.x < 64) {
    int r = r0 + threadIdx.x;
    float dg = degsum2[r] - W2f[(size_t)r * 1024 + r];  // exclude diag (exact ints)
    float dv = rsqrtf(dg + 1.f);
    ds[threadIdx.x] = dv;
    if (bx == 0) dinv2v[r] = dv;
  }
  for (int it = 0; it < 16; ++it) {
    int idx = (it << 8) + threadIdx.x;
    int r = idx >> 6, c = idx & 63;
    float v = W2f[(size_t)(r0 + r) * 1024 + c0 + c];
    if (r0 + r == c0 + c) v = 1.f;  // A2 = W2_diagzeroed + I
    t[r][c] = v;
  }
  __syncthreads();
  for (int it = 0; it < 16; ++it) {
    int idx = (it << 8) + threadIdx.x;
    int rr = idx >> 6, cc = idx & 63;
    W2Tb[(size_t)(c0 + rr) * 1024 + r0 + cc] = f2bf(t[cc][rr] * ds[cc]);
  }
}

// reduce + GCN epilogue (agg includes +I); optional scatter-add
__global__ __launch_bounds__(256) void epi_red1(const float* __restrict__ Pf,
                                                const float* __restrict__ dinv,
                                                const float* __restrict__ bias,
                                                const int* __restrict__ permS,
                                                float* __restrict__ scatterDst,
                                                float* __restrict__ outp, int M, int N,
                                                int splits) {
  int g = blockIdx.x * 256 + threadIdx.x;
  size_t base = (size_t)g * 4;
  size_t MN = (size_t)M * N;
  if (base >= MN) return;
  int r = (int)(base / N), c = (int)(base % N);
  float4 a = *(const float4*)&Pf[base];
  for (int s = 1; s < splits; ++s) {
    float4 p = *(const float4*)&Pf[s * MN + base];
    a.x += p.x; a.y += p.y; a.z += p.z; a.w += p.w;
  }
  float dv = dinv[r];
  float4 bb = *(const float4*)&bias[c];
  float4 o;
  o.x = fmaxf(dv * a.x + bb.x, 0.f);
  o.y = fmaxf(dv * a.y + bb.y, 0.f);
  o.z = fmaxf(dv * a.z + bb.z, 0.f);
  o.w = fmaxf(dv * a.w + bb.w, 0.f);
  if (outp) *(float4*)&outp[base] = o;
  if (permS) {
    float4* d = (float4*)&scatterDst[(size_t)permS[r] * N + c];
    float4 cur = *d;
    cur.x += o.x; cur.y += o.y; cur.z += o.z; cur.w += o.w;
    *d = cur;
  }
}

// reduce + relu + pool-2 score. M=2048, N=512. 2 rows/block.
__global__ __launch_bounds__(256) void epi_red1s(const float* __restrict__ Pf,
                                                 const float* __restrict__ dinv,
                                                 const float* __restrict__ bias,
                                                 const float* __restrict__ pvec,
                                                 float* __restrict__ sc,
                                                 float* __restrict__ outp, int splits) {
  __shared__ float shs[2][2][2];
  int li = threadIdx.x & 127;
  int lr = threadIdx.x >> 7;
  int r = blockIdx.x * 2 + lr;
  size_t base = (size_t)r * 512 + li * 4;
  const size_t MN = (size_t)2048 * 512;
  float4 a = *(const float4*)&Pf[base];
  for (int s = 1; s < splits; ++s) {
    float4 p = *(const float4*)&Pf[s * MN + base];
    a.x += p.x; a.y += p.y; a.z += p.z; a.w += p.w;
  }
  float dv = dinv[r];
  float4 bb = *(const float4*)&bias[li * 4];
  float4 o;
  o.x = fmaxf(dv * a.x + bb.x, 0.f);
  o.y = fmaxf(dv * a.y + bb.y, 0.f);
  o.z = fmaxf(dv * a.z + bb.z, 0.f);
  o.w = fmaxf(dv * a.w + bb.w, 0.f);
  *(float4*)&outp[base] = o;
  float4 pv = *(const float4*)&pvec[li * 4];
  float s1 = pv.x * pv.x + pv.y * pv.y + pv.z * pv.z + pv.w * pv.w;
  float s2 = o.x * pv.x + o.y * pv.y + o.z * pv.z + o.w * pv.w;
#pragma unroll
  for (int t = 32; t > 0; t >>= 1) {
    s1 += __shfl_down(s1, t, 64);
    s2 += __shfl_down(s2, t, 64);
  }
  int wir = (threadIdx.x >> 6) & 1;
  if ((threadIdx.x & 63) == 0) { shs[lr][wir][0] = s1; shs[lr][wir][1] = s2; }
  __syncthreads();
  if ((threadIdx.x & 127) == 0) {
    float S1 = shs[lr][0][0] + shs[lr][1][0];
    float S2 = shs[lr][0][1] + shs[lr][1][1];
    sc[r] = tanhf(S2 / sqrtf(S1));
  }
}

// level-0 GCN epilogue + (optional) pool score. C=256: row == one wave.
template <int C, bool SCORE>
__global__ __launch_bounds__(256) void gcn_spmm4(const int* __restrict__ iptr,
                                                 const int* __restrict__ isrc,
                                                 const float* __restrict__ Z,
                                                 const float* __restrict__ dinv,
                                                 const float* __restrict__ bias,
                                                 const float* __restrict__ pvec,
                                                 float* __restrict__ sc,
                                                 float* __restrict__ outp) {
  constexpr int L = C / 4;
  int li = threadIdx.x % L;
  int i = blockIdx.x * (256 / L) + threadIdx.x / L;
  float4 acc = *(const float4*)(Z + (size_t)i * C + li * 4);
  int beg = iptr[i], end = iptr[i + 1];
  for (int e = beg; e < end; ++e) {
    float4 z = *(const float4*)(Z + (size_t)isrc[e] * C + li * 4);
    acc.x += z.x; acc.y += z.y; acc.z += z.z; acc.w += z.w;
  }
  float d = dinv[i];
  float4 bb = *(const float4*)(bias + li * 4);
  float4 o;
  o.x = fmaxf(d * acc.x + bb.x, 0.f);
  o.y = fmaxf(d * acc.y + bb.y, 0.f);
  o.z = fmaxf(d * acc.z + bb.z, 0.f);
  o.w = fmaxf(d * acc.w + bb.w, 0.f);
  *(float4*)(outp + (size_t)i * C + li * 4) = o;
  if (SCORE) {
    float4 pv = *(const float4*)(pvec + li * 4);
    float s1 = pv.x * pv.x + pv.y * pv.y + pv.z * pv.z + pv.w * pv.w;
    float s2 = o.x * pv.x + o.y * pv.y + o.z * pv.z + o.w * pv.w;
#pragma unroll
    for (int t = 32; t > 0; t >>= 1) {
      s1 += __shfl_down(s1, t, 64);
      s2 += __shfl_down(s2, t, 64);
    }
    if ((threadIdx.x & 63) == 0) sc[i] = tanhf(s2 / sqrtf(s1));
  }
}

// ---- top-k via radix select ----
__global__ __launch_bounds__(1024) void topk_select(const float* __restrict__ score,
                                                    int n, int k, int* __restrict__ perm,
                                                    float* __restrict__ vals,
                                                    int* __restrict__ rank) {
  __shared__ unsigned int keys[4096];
  __shared__ int hist[256];
  __shared__ int wsums[16];
  __shared__ unsigned int sh_prefix;
  __shared__ int sh_rem;
  int t = threadIdx.x;
  int m = n >> 10;
  for (int i = t; i < n; i += 1024) {
    unsigned int u = __float_as_uint(score[i]);
    keys[i] = u ^ ((unsigned int)((int)u >> 31) | 0x80000000u);
  }
  if (t == 0) { sh_prefix = 0u; sh_rem = k; }
  __syncthreads();
  for (int round = 0; round < 4; ++round) {
    int shift = 24 - (round << 3);
    if (t < 256) hist[t] = 0;
    __syncthreads();
    unsigned int prefix = sh_prefix;
    unsigned int maskhi = (round == 0) ? 0u : (0xFFFFFFFFu << (shift + 8));
    for (int i = t; i < n; i += 1024) {
      unsigned int kk = keys[i];
      if ((kk & maskhi) == prefix) atomicAdd(&hist[(kk >> shift) & 255], 1);
    }
    __syncthreads();
    if (t == 0) {
      int rem = sh_rem, acc = 0, b = 255;
      for (; b > 0; --b) {
        if (acc + hist[b] >= rem) break;
        acc += hist[b];
      }
      sh_rem = rem - acc;
      sh_prefix = prefix | ((unsigned int)b << shift);
    }
    __syncthreads();
  }
  unsigned int thr = sh_prefix;
  int need = sh_rem;
  int base = t * m;
  int f[4];
  int cnt = 0;
#pragma unroll
  for (int j = 0; j < 4; ++j) {
    f[j] = 0;
    if (j < m) { f[j] = (keys[base + j] == thr) ? 1 : 0; cnt += f[j]; }
  }
  int ex = blockScanExclusive(cnt, wsums);
  int sel[4];
  int scnt = 0;
#pragma unroll
  for (int j = 0; j < 4; ++j) {
    sel[j] = 0;
    if (j < m) {
      unsigned int kk = keys[base + j];
      sel[j] = (kk > thr) || (kk == thr && ex < need);
      ex += f[j];
      scnt += sel[j];
    }
  }
  int pos = blockScanExclusive(scnt, wsums);
#pragma unroll
  for (int j = 0; j < 4; ++j) {
    if (j < m) {
      int i = base + j;
      if (sel[j]) {
        unsigned int kk = keys[i];
        unsigned int u = (kk & 0x80000000u) ? (kk ^ 0x80000000u) : ~kk;
        perm[pos] = i;
        vals[pos] = __uint_as_float(u);
        rank[i] = pos;
        pos++;
      } else {
        rank[i] = -1;
      }
    }
  }
}

// A1[a,b] = W1+I (bf16, integer-exact, diag=1) + dinv1; wave-parallel
__global__ __launch_bounds__(256) void build_W1(const int* __restrict__ optr,
                                                const int* __restrict__ odst,
                                                const int* __restrict__ perm1,
                                                const int* __restrict__ rank1,
                                                unsigned short* __restrict__ W1b,
                                                float* __restrict__ dinv1) {
  __shared__ float row[2048];
  int a = blockIdx.x;
  int pa = perm1[a];
  for (int i = threadIdx.x; i < 2048; i += 256) row[i] = 0.f;
  __syncthreads();
  int kbeg = optr[pa], kend = optr[pa + 1];
  int nk = kend - kbeg + 1;
  int wv = threadIdx.x >> 6, lane = threadIdx.x & 63;
  for (int kidx = wv; kidx < nk; kidx += 4) {
    int k = (kidx == 0) ? pa : odst[kbeg + kidx - 1];
    int jbeg = optr[k], jend = optr[k + 1];
    for (int jj = jbeg - 1 + lane; jj < jend; jj += 64) {
      int j = (jj < jbeg) ? k : odst[jj];
      int rb = rank1[j];
      if (rb >= 0) atomicAdd(&row[rb], 1.0f);
    }
  }
  __syncthreads();
  float ssum = 0.f;
  for (int i = threadIdx.x; i < 2048; i += 256) {
    float v = row[i];
    W1b[(size_t)a * 2048 + i] = f2bf((i == a) ? 1.f : v);  // A1 = W1_offdiag + I
    ssum += (i == a) ? 0.f : v;
  }
  float t = blockReduceSum256(ssum);
  if (threadIdx.x == 0) dinv1[a] = rsqrtf(t + 1.0f);
}

__device__ void mean_cols_body(int c, const float* __restrict__ X, int R, int C,
                               float* __restrict__ outp) {
  float s = 0.f;
  for (int r = threadIdx.x; r < R; r += 256) s += X[(size_t)r * C + c];
  float t = blockReduceSum256(s);
  if (threadIdx.x == 0) outp[c] = t / (float)R;
}

__global__ __launch_bounds__(256) void fused_mean_up1a(
    const float* xb, float* meanOut, const float* x1b, const unsigned short* t3T,
    const float* dinv1, unsigned short* SAbT) {
  __shared__ char smem[16640];
  if (blockIdx.x < 512) mean_cols_body(blockIdx.x, xb, 1024, 512, meanOut);
  else gemm_e_body(smem, blockIdx.x - 512, x1b, t3T, nullptr, nullptr, dinv1, 1,
                   nullptr, SAbT, 2048, 256, 512, 4);
}

// ---------------- launcher ----------------
extern "C" void kernel_launch(void* const* d_in, const int* in_sizes, int n_in,
                              void* d_out, int out_size, void* d_ws, size_t ws_size,
                              hipStream_t stream) {
  const float* x      = (const float*)d_in[0];
  const int*   eidx   = (const int*)d_in[1];
  const float* theta0 = (const float*)d_in[2];
  const float* b0     = (const float*)d_in[3];
  const float* theta1 = (const float*)d_in[4];
  const float* b1     = (const float*)d_in[5];
  const float* theta2 = (const float*)d_in[6];
  const float* b2     = (const float*)d_in[7];
  const float* theta3 = (const float*)d_in[8];
  const float* b3     = (const float*)d_in[9];
  const float* theta4 = (const float*)d_in[10];
  const float* b4     = (const float*)d_in[11];
  const float* p1     = (const float*)d_in[12];
  const float* p2     = (const float*)d_in[13];
  const int E = in_sizes[1] / 2;
  const int* src = eidx;
  const int* dst = eidx + E;
  float* out = (float*)d_out;

  char* wsb = (char*)d_ws;
  size_t off = 0;
  auto alloc = [&](size_t bytes) -> void* {
    void* p = wsb + off;
    off = (off + bytes + 255) & ~(size_t)255;
    return p;
  };
  // zero-init block: cnt4 | degsum2 | W2f  (one memset)
  char* zblock = (char*)alloc((size_t)4 * N0 * 4 + P2K * 4 + (size_t)P2K * P2K * 4);
  int* cnt4 = (int*)zblock;
  float* degsum2 = (float*)(zblock + (size_t)4 * N0 * 4);
  float* W2f = (float*)(zblock + (size_t)4 * N0 * 4 + P2K * 4);
  size_t zbytes = (size_t)4 * N0 * 4 + P2K * 4 + (size_t)P2K * P2K * 4;

  int* optr  = (int*)alloc((N0 + 1) * 4);
  int* iptr  = (int*)alloc((N0 + 1) * 4);
  int* odst  = (int*)alloc((size_t)E * 4);
  int* isrc  = (int*)alloc((size_t)E * 4);
  int* perm1 = (int*)alloc(P1K * 4);
  int* rank1 = (int*)alloc(N0 * 4);
  int* perm2 = (int*)alloc(P2K * 4);
  int* rank2 = (int*)alloc(P1K * 4);
  float* dinv0 = (float*)alloc(N0 * 4);
  float* dinv1 = (float*)alloc(P1K * 4);
  float* dinv2v = (float*)alloc(P2K * 4);
  float* vals1 = (float*)alloc(P1K * 4);
  float* vals2 = (float*)alloc(P2K * 4);
  float* score = (float*)alloc(N0 * 4);
  float* x0  = (float*)alloc((size_t)N0 * 256 * 4);
  float* x1b = (float*)alloc((size_t)P1K * 512 * 4);
  float* xb  = (float*)alloc((size_t)P2K * 512 * 4);
  float* SA  = (float*)alloc((size_t)P1K * 512 * 4);        // Z scratch fp32
  float* Pf  = (float*)alloc((size_t)8 * 1048576 * 4);      // split-K partials (32 MB)
  unsigned short* W1b  = (unsigned short*)alloc((size_t)P1K * P1K * 2);
  unsigned short* W1bT = (unsigned short*)alloc((size_t)P1K * P1K * 2);
  unsigned short* W2Tb = (unsigned short*)alloc((size_t)P2K * P2K * 2);
  unsigned short* SAbT = (unsigned short*)alloc((size_t)524288 * 2);
  unsigned short* ZhT  = (unsigned short*)alloc((size_t)512 * 2048 * 2);
  unsigned short* ZlT  = (unsigned short*)alloc((size_t)512 * 2048 * 2);
  unsigned short* t0hT = (unsigned short*)alloc((size_t)256 * 128 * 2);
  unsigned short* t0lT = (unsigned short*)alloc((size_t)256 * 128 * 2);
  unsigned short* t1hT = (unsigned short*)alloc((size_t)512 * 256 * 2);
  unsigned short* t1lT = (unsigned short*)alloc((size_t)512 * 256 * 2);
  unsigned short* t2T  = (unsigned short*)alloc((size_t)512 * 512 * 2);
  unsigned short* t3T  = (unsigned short*)alloc((size_t)256 * 512 * 2);
  unsigned short* t4T  = (unsigned short*)alloc((size_t)128 * 256 * 2);
  (void)ws_size; (void)n_in; (void)out_size;

  int* co = cnt4;
  int* ci = cnt4 + N0;
  int* fo = cnt4 + 2 * N0;
  int* fi = cnt4 + 3 * N0;

  // --- graph build (count_edges || weight transposes) ---
  hipMemsetAsync(zblock, 0, zbytes, stream);
  fused_ce_conv<<<512 + 2304, 256, 0, stream>>>(src, dst, co, ci, E, theta0, theta1,
                                                theta2, theta3, theta4, t0hT, t0lT,
                                                t1hT, t1lT, t2T, t3T, t4T);
  exscan_dual<<<2, 1024, 0, stream>>>(co, ci, optr, iptr, dinv0);
  // fill_edges || gcn0 feature GEMM
  fused_fill_g3<<<512 + 256, 256, 0, stream>>>(src, dst, optr, iptr, fo, fi, odst, isrc,
                                               E, x, t0hT, t0lT, dinv0, SA);
  gcn_spmm4<256, true><<<1024, 256, 0, stream>>>(iptr, isrc, SA, dinv0, b0, p1, score, x0);

  // --- pool 1 ---
  topk_select<<<1, 1024, 0, stream>>>(score, 4096, 2048, perm1, vals1, rank1);
  build_W1<<<2048, 256, 0, stream>>>(optr, odst, perm1, rank1, W1b, dinv1);
  // A1 transpose || gcn1 feature GEMM
  fused_tr_g3<<<1024 + 256, 256, 0, stream>>>(W1b, W1bT, x0, t1hT, t1lT, perm1, vals1,
                                              dinv1, ZhT, ZlT);

  // --- gcn1 aggregation: A1^T (Zh+Zl), split-K 8 + pool-2 scores ---
  gemm_skd<8><<<256 * 8, 256, 0, stream>>>(W1bT, ZhT, ZlT, Pf, 2048, 512, 2048, 8, 256);
  epi_red1s<<<1024, 256, 0, stream>>>(Pf, dinv1, b1, p2, score, x1b, 8);

  // --- pool 2 ---
  topk_select<<<1, 1024, 0, stream>>>(score, 2048, 1024, perm2, vals2, rank2);
  // W2 build split-K 8 (+row sums) || gcn2 feature GEMM
  fused_w2_g2a<<<2048 + 128, 256, 0, stream>>>(W1b, W1bT, perm2, W2f, degsum2, x1b, t2T,
                                               vals2, SAbT);
  w2T<<<256, 256, 0, stream>>>(W2f, degsum2, W2Tb, dinv2v);

  // --- gcn2 aggregation: (A2 dinv2)^T Y, split-K 8; epilogue scatters into x1b ---
  gemm_sk<8><<<128 * 8, 256, 0, stream>>>(W2Tb, SAbT, Pf, 1024, 512, 1024, 8, 128);
  epi_red1<<<1024 * 512 / 1024, 256, 0, stream>>>(Pf, dinv2v, b2, perm2, x1b, xb,
                                                  1024, 512, 8);
  // summary mean || up1 feature GEMM
  fused_mean_up1a<<<512 + 128, 256, 0, stream>>>(xb, out + 524288, x1b, t3T, dinv1, SAbT);

  // --- up block 1: A1^T Z3, split-K 8; epilogue scatters into x0 ---
  gemm_sk<8><<<128 * 8, 256, 0, stream>>>(W1bT, SAbT, Pf, 2048, 256, 2048, 4, 128);
  epi_red1<<<2048 * 256 / 1024, 256, 0, stream>>>(Pf, dinv1, b3, perm1, x0, nullptr,
                                                  2048, 256, 8);

  // --- up block 0: feature GEMM + fp32 sparse agg -> out ---
  gemm_e_k<<<128, 256, 0, stream>>>(x0, t4T, nullptr, nullptr, dinv0, 1, SA, nullptr,
                                    4096, 128, 256, 2);
  gcn_spmm4<128, false><<<512, 256, 0, stream>>>(iptr, isrc, SA, dinv0, b4, nullptr,
                                                 nullptr, out);
}

// Round 13
// 302.735 us; speedup vs baseline: 1.1090x; 1.1090x over previous
//
#include <hip/hip_runtime.h>

#define N0 4096
#define P1K 2048
#define P2K 1024
#define SPLITS 4

typedef short bf16x8 __attribute__((ext_vector_type(8)));
typedef float f32x4 __attribute__((ext_vector_type(4)));

__device__ __forceinline__ unsigned short f2bf(float f) {
  unsigned int u = __float_as_uint(f);
  unsigned int r = (u + 0x7fff + ((u >> 16) & 1)) >> 16;
  return (unsigned short)r;
}
__device__ __forceinline__ float bf2f(unsigned short h) {
  unsigned int u = ((unsigned int)h) << 16;
  return __uint_as_float(u);
}

// ---------------- helpers ----------------
__device__ __forceinline__ float blockReduceSum256(float v) {
  __shared__ float sh[16];
  int lane = threadIdx.x & 63;
  int w = threadIdx.x >> 6;
#pragma unroll
  for (int o = 32; o > 0; o >>= 1) v += __shfl_down(v, o, 64);
  __syncthreads();
  if (lane == 0) sh[w] = v;
  __syncthreads();
  float r = 0.f;
  if (threadIdx.x == 0) {
    int nw = (blockDim.x + 63) >> 6;
    for (int i = 0; i < nw; ++i) r += sh[i];
  }
  return r;  // valid on thread 0 only
}

__device__ __forceinline__ int blockScanExclusive(int v, volatile int* wsums) {
  int lane = threadIdx.x & 63, w = threadIdx.x >> 6;
  int x = v;
#pragma unroll
  for (int o = 1; o < 64; o <<= 1) {
    int y = __shfl_up(x, o, 64);
    if (lane >= o) x += y;
  }
  if (lane == 63) wsums[w] = x;
  __syncthreads();
  if (threadIdx.x < 64) {
    int nw = blockDim.x >> 6;
    int s = (threadIdx.x < nw) ? wsums[threadIdx.x] : 0;
#pragma unroll
    for (int o = 1; o < 16; o <<= 1) {
      int y = __shfl_up(s, o, 64);
      if (lane >= o) s += y;
    }
    if (threadIdx.x < nw) wsums[threadIdx.x] = s;
  }
  __syncthreads();
  int base = (w > 0) ? wsums[w - 1] : 0;
  __syncthreads();
  return base + x - v;
}

// ---------------- graph build bodies ----------------
__device__ __forceinline__ void count_edges_body(int b, const int* __restrict__ src,
                                                 const int* __restrict__ dst,
                                                 int* __restrict__ co, int* __restrict__ ci,
                                                 int E) {
  int e = b * 256 + threadIdx.x;
  if (e < E) {
    atomicAdd(&co[src[e]], 1);
    atomicAdd(&ci[dst[e]], 1);
  }
}

__device__ __forceinline__ void conv_body(int b, const float* __restrict__ t0,
                                          const float* __restrict__ t1,
                                          const float* __restrict__ t2,
                                          const float* __restrict__ t3,
                                          const float* __restrict__ t4,
                                          unsigned short* __restrict__ o0h,
                                          unsigned short* __restrict__ o0l,
                                          unsigned short* __restrict__ o1h,
                                          unsigned short* __restrict__ o1l,
                                          unsigned short* __restrict__ o2,
                                          unsigned short* __restrict__ o3,
                                          unsigned short* __restrict__ o4) {
  int idx = b * 256 + threadIdx.x;
  if (idx < 32768) {
    int k = idx >> 8, n = idx & 255;
    float v = t0[idx];
    unsigned short h = f2bf(v);
    o0h[(size_t)n * 128 + k] = h;
    o0l[(size_t)n * 128 + k] = f2bf(v - bf2f(h));
  } else if (idx < 163840) {
    int i = idx - 32768;
    int k = i >> 9, n = i & 511;
    float v = t1[i];
    unsigned short h = f2bf(v);
    o1h[(size_t)n * 256 + k] = h;
    o1l[(size_t)n * 256 + k] = f2bf(v - bf2f(h));
  } else if (idx < 425984) {
    int i = idx - 163840;
    int k = i >> 9, n = i & 511;
    o2[(size_t)n * 512 + k] = f2bf(t2[i]);
  } else if (idx < 557056) {
    int i = idx - 425984;
    int k = i >> 8, n = i & 255;
    o3[(size_t)n * 512 + k] = f2bf(t3[i]);
  } else if (idx < 589824) {
    int i = idx - 557056;
    int k = i >> 7, n = i & 127;
    o4[(size_t)n * 256 + k] = f2bf(t4[i]);
  }
}

__global__ __launch_bounds__(256) void fused_ce_conv(
    const int* __restrict__ src, const int* __restrict__ dst, int* __restrict__ co,
    int* __restrict__ ci, int E, const float* t0, const float* t1, const float* t2,
    const float* t3, const float* t4, unsigned short* o0h, unsigned short* o0l,
    unsigned short* o1h, unsigned short* o1l, unsigned short* o2, unsigned short* o3,
    unsigned short* o4) {
  if (blockIdx.x < 512) count_edges_body(blockIdx.x, src, dst, co, ci, E);
  else conv_body(blockIdx.x - 512, t0, t1, t2, t3, t4, o0h, o0l, o1h, o1l, o2, o3, o4);
}

// block 0: co->optr (+dinv0), block 1: ci->iptr
__global__ __launch_bounds__(1024) void exscan_dual(const int* __restrict__ co,
                                                    const int* __restrict__ ci,
                                                    int* __restrict__ optr,
                                                    int* __restrict__ iptr,
                                                    float* __restrict__ dinv0) {
  __shared__ int ls[1024];
  const int* cnt = blockIdx.x ? ci : co;
  int* ptr = blockIdx.x ? iptr : optr;
  int t = threadIdx.x;
  int v0 = cnt[t * 4], v1 = cnt[t * 4 + 1], v2 = cnt[t * 4 + 2], v3 = cnt[t * 4 + 3];
  int s = v0 + v1 + v2 + v3;
  ls[t] = s;
  __syncthreads();
  for (int off = 1; off < 1024; off <<= 1) {
    int x = (t >= off) ? ls[t - off] : 0;
    __syncthreads();
    ls[t] += x;
    __syncthreads();
  }
  int ex = (t > 0) ? ls[t - 1] : 0;
  ptr[t * 4]     = ex;
  ptr[t * 4 + 1] = ex + v0;
  ptr[t * 4 + 2] = ex + v0 + v1;
  ptr[t * 4 + 3] = ex + v0 + v1 + v2;
  if (t == 1023) ptr[4096] = ex + s;
  if (blockIdx.x == 0) {
    dinv0[t * 4]     = rsqrtf((float)v0 + 1.f);
    dinv0[t * 4 + 1] = rsqrtf((float)v1 + 1.f);
    dinv0[t * 4 + 2] = rsqrtf((float)v2 + 1.f);
    dinv0[t * 4 + 3] = rsqrtf((float)v3 + 1.f);
  }
}

__device__ __forceinline__ void fill_body(int b, const int* __restrict__ src,
                                          const int* __restrict__ dst,
                                          const int* __restrict__ optr,
                                          const int* __restrict__ iptr,
                                          int* __restrict__ fo, int* __restrict__ fi,
                                          int* __restrict__ odst, int* __restrict__ isrc,
                                          int E) {
  int e = b * 256 + threadIdx.x;
  if (e < E) {
    int s = src[e], d = dst[e];
    odst[optr[s] + atomicAdd(&fo[s], 1)] = d;
    isrc[iptr[d] + atomicAdd(&fi[d], 1)] = s;
  }
}

// ---- fp32-emulated MFMA GEMM (3-term bf16 split) body; smem: 32768 B ----
template <bool TOUT>
__device__ void gemm3_body(char* smem, int bid, const float* __restrict__ A,
                           const unsigned short* __restrict__ BhT,
                           const unsigned short* __restrict__ BlT,
                           const int* __restrict__ permA, const float* __restrict__ valsA,
                           const float* __restrict__ dinv, float* __restrict__ C,
                           unsigned short* __restrict__ ChT, unsigned short* __restrict__ ClT,
                           int M, int N, int K, int nbx) {
  unsigned short* U = (unsigned short*)smem;
  unsigned short* Ah = U;
  unsigned short* Al = U + 4096;
  unsigned short* Bh = U + 8192;
  unsigned short* Bl = U + 12288;
  int tid = threadIdx.x;
  int by = bid / nbx, bx = bid % nbx;
  int row0 = by << 6, col0 = bx << 6;
  int l = tid & 63, wv = tid >> 6;
  int wr = (wv >> 1) << 5, wc = (wv & 1) << 5;
  f32x4 acc[2][2] = {};
  for (int k0 = 0; k0 < K; k0 += 64) {
#pragma unroll
    for (int it = 0; it < 2; ++it) {
      int idx = (it << 8) + tid;
      int r = idx >> 3, c8 = idx & 7;
      int sw = c8 ^ (r & 7);
      int row = row0 + r;
      int srow = permA ? permA[row] : row;
      float vs = valsA ? valsA[row] : 1.f;
      const float* Af = A + (size_t)srow * K + k0 + (c8 << 3);
      float4 f0 = *(const float4*)Af;
      float4 f1 = *(const float4*)(Af + 4);
      float vv[8] = {f0.x * vs, f0.y * vs, f0.z * vs, f0.w * vs,
                     f1.x * vs, f1.y * vs, f1.z * vs, f1.w * vs};
      uint4 uh, ul;
      unsigned short hh[8], ll[8];
#pragma unroll
      for (int q = 0; q < 8; ++q) {
        hh[q] = f2bf(vv[q]);
        ll[q] = f2bf(vv[q] - bf2f(hh[q]));
      }
      uh.x = (unsigned)hh[0] | ((unsigned)hh[1] << 16);
      uh.y = (unsigned)hh[2] | ((unsigned)hh[3] << 16);
      uh.z = (unsigned)hh[4] | ((unsigned)hh[5] << 16);
      uh.w = (unsigned)hh[6] | ((unsigned)hh[7] << 16);
      ul.x = (unsigned)ll[0] | ((unsigned)ll[1] << 16);
      ul.y = (unsigned)ll[2] | ((unsigned)ll[3] << 16);
      ul.z = (unsigned)ll[4] | ((unsigned)ll[5] << 16);
      ul.w = (unsigned)ll[6] | ((unsigned)ll[7] << 16);
      ((uint4*)Ah)[(r << 3) + sw] = uh;
      ((uint4*)Al)[(r << 3) + sw] = ul;
      ((uint4*)Bh)[(r << 3) + sw] =
          *(const uint4*)(BhT + (size_t)(col0 + r) * K + k0 + (c8 << 3));
      ((uint4*)Bl)[(r << 3) + sw] =
          *(const uint4*)(BlT + (size_t)(col0 + r) * K + k0 + (c8 << 3));
    }
    __syncthreads();
#pragma unroll
    for (int kk2 = 0; kk2 < 2; ++kk2) {
      int ch = (kk2 << 2) + (l >> 4);
      int ra = wr + (l & 15), rb = ra + 16;
      int ca = wc + (l & 15), cb = ca + 16;
      int oa0 = (ra << 6) + ((ch ^ (ra & 7)) << 3);
      int oa1 = (rb << 6) + ((ch ^ (rb & 7)) << 3);
      int ob0 = (ca << 6) + ((ch ^ (ca & 7)) << 3);
      int ob1 = (cb << 6) + ((ch ^ (cb & 7)) << 3);
      bf16x8 ah0 = *(const bf16x8*)&Ah[oa0], ah1 = *(const bf16x8*)&Ah[oa1];
      bf16x8 al0 = *(const bf16x8*)&Al[oa0], al1 = *(const bf16x8*)&Al[oa1];
      bf16x8 bh0 = *(const bf16x8*)&Bh[ob0], bh1 = *(const bf16x8*)&Bh[ob1];
      bf16x8 bl0 = *(const bf16x8*)&Bl[ob0], bl1 = *(const bf16x8*)&Bl[ob1];
      acc[0][0] = __builtin_amdgcn_mfma_f32_16x16x32_bf16(ah0, bh0, acc[0][0], 0, 0, 0);
      acc[0][1] = __builtin_amdgcn_mfma_f32_16x16x32_bf16(ah0, bh1, acc[0][1], 0, 0, 0);
      acc[1][0] = __builtin_amdgcn_mfma_f32_16x16x32_bf16(ah1, bh0, acc[1][0], 0, 0, 0);
      acc[1][1] = __builtin_amdgcn_mfma_f32_16x16x32_bf16(ah1, bh1, acc[1][1], 0, 0, 0);
      acc[0][0] = __builtin_amdgcn_mfma_f32_16x16x32_bf16(ah0, bl0, acc[0][0], 0, 0, 0);
      acc[0][1] = __builtin_amdgcn_mfma_f32_16x16x32_bf16(ah0, bl1, acc[0][1], 0, 0, 0);
      acc[1][0] = __builtin_amdgcn_mfma_f32_16x16x32_bf16(ah1, bl0, acc[1][0], 0, 0, 0);
      acc[1][1] = __builtin_amdgcn_mfma_f32_16x16x32_bf16(ah1, bl1, acc[1][1], 0, 0, 0);
      acc[0][0] = __builtin_amdgcn_mfma_f32_16x16x32_bf16(al0, bh0, acc[0][0], 0, 0, 0);
      acc[0][1] = __builtin_amdgcn_mfma_f32_16x16x32_bf16(al0, bh1, acc[0][1], 0, 0, 0);
      acc[1][0] = __builtin_amdgcn_mfma_f32_16x16x32_bf16(al1, bh0, acc[1][0], 0, 0, 0);
      acc[1][1] = __builtin_amdgcn_mfma_f32_16x16x32_bf16(al1, bh1, acc[1][1], 0, 0, 0);
    }
    __syncthreads();
  }
  int lrow = (l >> 4) << 2, lcol = l & 15;
  float* tf = (float*)smem;
#pragma unroll
  for (int i = 0; i < 2; ++i)
#pragma unroll
    for (int j = 0; j < 2; ++j) {
      int lc = wc + (j << 4) + lcol;
      int lr0 = wr + (i << 4) + lrow;
      int c = col0 + lc;
#pragma unroll
      for (int rg = 0; rg < 4; ++rg) {
        int lr = lr0 + rg;
        int r = row0 + lr;
        float dv = dinv ? dinv[r] : 1.f;
        float v = acc[i][j][rg] * dv;
        if (C) C[(size_t)r * N + c] = v;
        if (TOUT) tf[lr * 65 + lc] = v;
      }
    }
  if (TOUT) {
    __syncthreads();
    for (int it = 0; it < 16; ++it) {
      int idx = (it << 8) + tid;
      int rr = idx >> 6, cc = idx & 63;
      float v = tf[cc * 65 + rr];
      unsigned short h = f2bf(v);
      size_t o = (size_t)(col0 + rr) * M + row0 + cc;
      ChT[o] = h;
      ClT[o] = f2bf(v - bf2f(h));
    }
  }
}

__global__ __launch_bounds__(256) void fused_fill_g3(
    const int* src, const int* dst, const int* optr, const int* iptr, int* fo, int* fi,
    int* odst, int* isrc, int E, const float* x, const unsigned short* t0hT,
    const unsigned short* t0lT, const float* dinv0, float* SA) {
  __shared__ char smem[32768];
  if (blockIdx.x < 512) fill_body(blockIdx.x, src, dst, optr, iptr, fo, fi, odst, isrc, E);
  else gemm3_body<false>(smem, blockIdx.x - 512, x, t0hT, t0lT, nullptr, nullptr, dinv0,
                         SA, nullptr, nullptr, 4096, 256, 128, 4);
}

// ---- 64x64-tile bf16 transpose body ----
__device__ void transpose_body(char* smem, int bid, const unsigned short* __restrict__ in,
                               unsigned short* __restrict__ out, int n) {
  unsigned short* t = (unsigned short*)smem;  // [64][65]
  int nb = n >> 6;
  int bx = bid % nb, by = bid / nb;
  int r0 = by << 6, c0 = bx << 6;
  for (int it = 0; it < 16; ++it) {
    int idx = (it << 8) + threadIdx.x;
    int r = idx >> 6, c = idx & 63;
    t[r * 65 + c] = in[(size_t)(r0 + r) * n + c0 + c];
  }
  __syncthreads();
  for (int it = 0; it < 16; ++it) {
    int idx = (it << 8) + threadIdx.x;
    int r = idx >> 6, c = idx & 63;
    out[(size_t)(c0 + r) * n + r0 + c] = t[c * 65 + r];
  }
}

__global__ __launch_bounds__(256) void fused_tr_g3(
    const unsigned short* W1b, unsigned short* W1bT, const float* x0,
    const unsigned short* t1hT, const unsigned short* t1lT, const int* perm1,
    const float* vals1, const float* dinv1, unsigned short* ZhT, unsigned short* ZlT) {
  __shared__ char smem[32768];
  if (blockIdx.x < 1024) transpose_body(smem, blockIdx.x, W1b, W1bT, 2048);
  else gemm3_body<true>(smem, blockIdx.x - 1024, x0, t1hT, t1lT, perm1, vals1, dinv1,
                        nullptr, ZhT, ZlT, 2048, 512, 256, 8);
}

// ---- dual-B split-K GEMM: Pf[s] = A @ (Bh + Bl) (gcn1: A1^T (Zh+Zl)) ----
__global__ __launch_bounds__(256) void gemm_skd(const unsigned short* __restrict__ A,
                                                const unsigned short* __restrict__ BhT,
                                                const unsigned short* __restrict__ BlT,
                                                float* __restrict__ Pf,
                                                int M, int N, int K, int nbx, int nb2d) {
  __shared__ unsigned short As[4096], Bh[4096], Bl[4096];
  int tid = threadIdx.x;
  int s = blockIdx.x / nb2d;
  int r2 = blockIdx.x % nb2d;
  int by = r2 / nbx, bx = r2 % nbx;
  int row0 = by << 6, col0 = bx << 6;
  int kc = K / SPLITS;
  int ks = s * kc, ke = ks + kc;
  int l = tid & 63, wv = tid >> 6;
  int wr = (wv >> 1) << 5, wc = (wv & 1) << 5;
  f32x4 acc[2][2] = {};
  for (int k0 = ks; k0 < ke; k0 += 64) {
#pragma unroll
    for (int it = 0; it < 2; ++it) {
      int idx = (it << 8) + tid;
      int r = idx >> 3, c8 = idx & 7;
      int sw = c8 ^ (r & 7);
      ((uint4*)As)[(r << 3) + sw] =
          *(const uint4*)(A + (size_t)(row0 + r) * K + k0 + (c8 << 3));
      ((uint4*)Bh)[(r << 3) + sw] =
          *(const uint4*)(BhT + (size_t)(col0 + r) * K + k0 + (c8 << 3));
      ((uint4*)Bl)[(r << 3) + sw] =
          *(const uint4*)(BlT + (size_t)(col0 + r) * K + k0 + (c8 << 3));
    }
    __syncthreads();
#pragma unroll
    for (int kk2 = 0; kk2 < 2; ++kk2) {
      int ch = (kk2 << 2) + (l >> 4);
      int ra = wr + (l & 15), rb = ra + 16;
      int ca = wc + (l & 15), cb = ca + 16;
      bf16x8 a0 = *(const bf16x8*)&As[(ra << 6) + ((ch ^ (ra & 7)) << 3)];
      bf16x8 a1 = *(const bf16x8*)&As[(rb << 6) + ((ch ^ (rb & 7)) << 3)];
      bf16x8 bh0 = *(const bf16x8*)&Bh[(ca << 6) + ((ch ^ (ca & 7)) << 3)];
      bf16x8 bh1 = *(const bf16x8*)&Bh[(cb << 6) + ((ch ^ (cb & 7)) << 3)];
      bf16x8 bl0 = *(const bf16x8*)&Bl[(ca << 6) + ((ch ^ (ca & 7)) << 3)];
      bf16x8 bl1 = *(const bf16x8*)&Bl[(cb << 6) + ((ch ^ (cb & 7)) << 3)];
      acc[0][0] = __builtin_amdgcn_mfma_f32_16x16x32_bf16(a0, bh0, acc[0][0], 0, 0, 0);
      acc[0][1] = __builtin_amdgcn_mfma_f32_16x16x32_bf16(a0, bh1, acc[0][1], 0, 0, 0);
      acc[1][0] = __builtin_amdgcn_mfma_f32_16x16x32_bf16(a1, bh0, acc[1][0], 0, 0, 0);
      acc[1][1] = __builtin_amdgcn_mfma_f32_16x16x32_bf16(a1, bh1, acc[1][1], 0, 0, 0);
      acc[0][0] = __builtin_amdgcn_mfma_f32_16x16x32_bf16(a0, bl0, acc[0][0], 0, 0, 0);
      acc[0][1] = __builtin_amdgcn_mfma_f32_16x16x32_bf16(a0, bl1, acc[0][1], 0, 0, 0);
      acc[1][0] = __builtin_amdgcn_mfma_f32_16x16x32_bf16(a1, bl0, acc[1][0], 0, 0, 0);
      acc[1][1] = __builtin_amdgcn_mfma_f32_16x16x32_bf16(a1, bl1, acc[1][1], 0, 0, 0);
    }
    __syncthreads();
  }
  int lrow = (l >> 4) << 2, lcol = l & 15;
  float* P = Pf + (size_t)s * M * N;
#pragma unroll
  for (int i = 0; i < 2; ++i)
#pragma unroll
    for (int j = 0; j < 2; ++j) {
      int c = col0 + wc + (j << 4) + lcol;
      int r0 = row0 + wr + (i << 4) + lrow;
#pragma unroll
      for (int rg = 0; rg < 4; ++rg)
        P[(size_t)(r0 + rg) * N + c] = acc[i][j][rg];
    }
}

// ---- split-K bf16 MFMA GEMM (A bf16) ----
__global__ __launch_bounds__(256) void gemm_sk(const unsigned short* __restrict__ A,
                                               const unsigned short* __restrict__ BT,
                                               float* __restrict__ Pf,
                                               int M, int N, int K, int nbx, int nb2d) {
  __shared__ unsigned short As[4096];
  __shared__ unsigned short Bs[4096];
  int tid = threadIdx.x;
  int s = blockIdx.x / nb2d;
  int r2 = blockIdx.x % nb2d;
  int by = r2 / nbx, bx = r2 % nbx;
  int row0 = by << 6, col0 = bx << 6;
  int kc = K / SPLITS;
  int ks = s * kc, ke = ks + kc;
  int l = tid & 63, wv = tid >> 6;
  int wr = (wv >> 1) << 5, wc = (wv & 1) << 5;
  f32x4 acc[2][2] = {};
  for (int k0 = ks; k0 < ke; k0 += 64) {
#pragma unroll
    for (int it = 0; it < 2; ++it) {
      int idx = (it << 8) + tid;
      int r = idx >> 3, c8 = idx & 7;
      int sw = c8 ^ (r & 7);
      ((uint4*)As)[(r << 3) + sw] =
          *(const uint4*)(A + (size_t)(row0 + r) * K + k0 + (c8 << 3));
      ((uint4*)Bs)[(r << 3) + sw] =
          *(const uint4*)(BT + (size_t)(col0 + r) * K + k0 + (c8 << 3));
    }
    __syncthreads();
#pragma unroll
    for (int kk2 = 0; kk2 < 2; ++kk2) {
      int ch = (kk2 << 2) + (l >> 4);
      int ra = wr + (l & 15), rb = ra + 16;
      int ca = wc + (l & 15), cb = ca + 16;
      bf16x8 a0 = *(const bf16x8*)&As[(ra << 6) + ((ch ^ (ra & 7)) << 3)];
      bf16x8 a1 = *(const bf16x8*)&As[(rb << 6) + ((ch ^ (rb & 7)) << 3)];
      bf16x8 b0 = *(const bf16x8*)&Bs[(ca << 6) + ((ch ^ (ca & 7)) << 3)];
      bf16x8 b1 = *(const bf16x8*)&Bs[(cb << 6) + ((ch ^ (cb & 7)) << 3)];
      acc[0][0] = __builtin_amdgcn_mfma_f32_16x16x32_bf16(a0, b0, acc[0][0], 0, 0, 0);
      acc[0][1] = __builtin_amdgcn_mfma_f32_16x16x32_bf16(a0, b1, acc[0][1], 0, 0, 0);
      acc[1][0] = __builtin_amdgcn_mfma_f32_16x16x32_bf16(a1, b0, acc[1][0], 0, 0, 0);
      acc[1][1] = __builtin_amdgcn_mfma_f32_16x16x32_bf16(a1, b1, acc[1][1], 0, 0, 0);
    }
    __syncthreads();
  }
  int lrow = (l >> 4) << 2, lcol = l & 15;
  float* P = Pf + (size_t)s * M * N;
#pragma unroll
  for (int i = 0; i < 2; ++i)
#pragma unroll
    for (int j = 0; j < 2; ++j) {
      int c = col0 + wc + (j << 4) + lcol;
      int r0 = row0 + wr + (i << 4) + lrow;
#pragma unroll
      for (int rg = 0; rg < 4; ++rg)
        P[(size_t)(r0 + rg) * N + c] = acc[i][j][rg];
    }
}

// ---- non-split GEMM with fused epilogue; smem: 16640 B ----
__device__ void gemm_e_body(char* smem, int bid, const float* __restrict__ A,
                            const unsigned short* __restrict__ BT,
                            const int* __restrict__ permA, const float* __restrict__ valsA,
                            const float* __restrict__ dinv, int dm,
                            float* __restrict__ Cf, unsigned short* __restrict__ CbT,
                            int M, int N, int K, int nbx) {
  unsigned short* As = (unsigned short*)smem;
  unsigned short* Bs = (unsigned short*)(smem + 8192);
  int tid = threadIdx.x;
  int by = bid / nbx, bx = bid % nbx;
  int row0 = by << 6, col0 = bx << 6;
  int l = tid & 63, wv = tid >> 6;
  int wr = (wv >> 1) << 5, wc = (wv & 1) << 5;
  f32x4 acc[2][2] = {};
  for (int k0 = 0; k0 < K; k0 += 64) {
#pragma unroll
    for (int it = 0; it < 2; ++it) {
      int idx = (it << 8) + tid;
      int r = idx >> 3, c8 = idx & 7;
      int sw = c8 ^ (r & 7);
      int row = row0 + r;
      int srow = permA ? permA[row] : row;
      float vs = valsA ? valsA[row] : 1.f;
      const float* Af = A + (size_t)srow * K + k0 + (c8 << 3);
      float4 f0 = *(const float4*)Af;
      float4 f1 = *(const float4*)(Af + 4);
      uint4 u;
      u.x = (unsigned)f2bf(f0.x * vs) | ((unsigned)f2bf(f0.y * vs) << 16);
      u.y = (unsigned)f2bf(f0.z * vs) | ((unsigned)f2bf(f0.w * vs) << 16);
      u.z = (unsigned)f2bf(f1.x * vs) | ((unsigned)f2bf(f1.y * vs) << 16);
      u.w = (unsigned)f2bf(f1.z * vs) | ((unsigned)f2bf(f1.w * vs) << 16);
      ((uint4*)As)[(r << 3) + sw] = u;
      ((uint4*)Bs)[(r << 3) + sw] =
          *(const uint4*)(BT + (size_t)(col0 + r) * K + k0 + (c8 << 3));
    }
    __syncthreads();
#pragma unroll
    for (int kk2 = 0; kk2 < 2; ++kk2) {
      int ch = (kk2 << 2) + (l >> 4);
      int ra = wr + (l & 15), rb = ra + 16;
      int ca = wc + (l & 15), cb = ca + 16;
      bf16x8 a0 = *(const bf16x8*)&As[(ra << 6) + ((ch ^ (ra & 7)) << 3)];
      bf16x8 a1 = *(const bf16x8*)&As[(rb << 6) + ((ch ^ (rb & 7)) << 3)];
      bf16x8 b0 = *(const bf16x8*)&Bs[(ca << 6) + ((ch ^ (ca & 7)) << 3)];
      bf16x8 b1 = *(const bf16x8*)&Bs[(cb << 6) + ((ch ^ (cb & 7)) << 3)];
      acc[0][0] = __builtin_amdgcn_mfma_f32_16x16x32_bf16(a0, b0, acc[0][0], 0, 0, 0);
      acc[0][1] = __builtin_amdgcn_mfma_f32_16x16x32_bf16(a0, b1, acc[0][1], 0, 0, 0);
      acc[1][0] = __builtin_amdgcn_mfma_f32_16x16x32_bf16(a1, b0, acc[1][0], 0, 0, 0);
      acc[1][1] = __builtin_amdgcn_mfma_f32_16x16x32_bf16(a1, b1, acc[1][1], 0, 0, 0);
    }
    __syncthreads();
  }
  int lrow = (l >> 4) << 2, lcol = l & 15;
  float* tf = (float*)smem;
#pragma unroll
  for (int i = 0; i < 2; ++i)
#pragma unroll
    for (int j = 0; j < 2; ++j) {
      int lc = wc + (j << 4) + lcol;
      int lr0 = wr + (i << 4) + lrow;
      int c = col0 + lc;
#pragma unroll
      for (int rg = 0; rg < 4; ++rg) {
        int lr = lr0 + rg;
        int r = row0 + lr;
        float dv = (dm == 1) ? dinv[r] : 1.f;
        float v = acc[i][j][rg] * dv;
        if (Cf) Cf[(size_t)r * N + c] = v;
        if (CbT) tf[lr * 65 + lc] = v;
      }
    }
  if (CbT) {
    __syncthreads();
    for (int it = 0; it < 16; ++it) {
      int idx = (it << 8) + tid;
      int rr = idx >> 6, cc = idx & 63;
      CbT[(size_t)(col0 + rr) * M + row0 + cc] = f2bf(tf[cc * 65 + rr]);
    }
  }
}

__global__ __launch_bounds__(256) void gemm_e_k(const float* A, const unsigned short* BT,
                                                const int* permA, const float* valsA,
                                                const float* dinv, int dm, float* Cf,
                                                unsigned short* CbT, int M, int N, int K,
                                                int nbx) {
  __shared__ char smem[16640];
  gemm_e_body(smem, blockIdx.x, A, BT, permA, valsA, dinv, dm, Cf, CbT, M, N, K, nbx);
}

// ---- W2f += A1[p2,:]@A1[:,p2] split-K 4 + row-sum atomics; smem: 16896 B ----
__device__ void mm_w2_body(char* smem, int bid, const unsigned short* __restrict__ Wb,
                           const unsigned short* __restrict__ WbT,
                           const int* __restrict__ perm2, float* __restrict__ W2f,
                           float* __restrict__ degsum2) {
  unsigned short* As = (unsigned short*)smem;
  unsigned short* Bs = (unsigned short*)(smem + 8192);
  int* pr = (int*)(smem + 16384);
  int* pc = pr + 64;
  int tid = threadIdx.x;
  int s = bid >> 8;
  int t2d = bid & 255;
  int bx = t2d & 15, by = t2d >> 4;
  int row0 = by << 6, col0 = bx << 6;
  int ks = s * 512, ke = ks + 512;
  if (tid < 64) pr[tid] = perm2[row0 + tid];
  else if (tid < 128) pc[tid - 64] = perm2[col0 + tid - 128 + 64];
  __syncthreads();
  int l = tid & 63, wv = tid >> 6;
  int wr = (wv >> 1) << 5, wc = (wv & 1) << 5;
  f32x4 acc[2][2] = {};
  for (int k0 = ks; k0 < ke; k0 += 64) {
#pragma unroll
    for (int it = 0; it < 2; ++it) {
      int idx = (it << 8) + tid;
      int r = idx >> 3, c8 = idx & 7;
      int sw = c8 ^ (r & 7);
      ((uint4*)As)[(r << 3) + sw] =
          *(const uint4*)(Wb + (size_t)pr[r] * 2048 + k0 + (c8 << 3));
      ((uint4*)Bs)[(r << 3) + sw] =
          *(const uint4*)(WbT + (size_t)pc[r] * 2048 + k0 + (c8 << 3));
    }
    __syncthreads();
#pragma unroll
    for (int kk2 = 0; kk2 < 2; ++kk2) {
      int ch = (kk2 << 2) + (l >> 4);
      int ra = wr + (l & 15), rb = ra + 16;
      int ca = wc + (l & 15), cb = ca + 16;
      bf16x8 a0 = *(const bf16x8*)&As[(ra << 6) + ((ch ^ (ra & 7)) << 3)];
      bf16x8 a1 = *(const bf16x8*)&As[(rb << 6) + ((ch ^ (rb & 7)) << 3)];
      bf16x8 b0 = *(const bf16x8*)&Bs[(ca << 6) + ((ch ^ (ca & 7)) << 3)];
      bf16x8 b1 = *(const bf16x8*)&Bs[(cb << 6) + ((ch ^ (cb & 7)) << 3)];
      acc[0][0] = __builtin_amdgcn_mfma_f32_16x16x32_bf16(a0, b0, acc[0][0], 0, 0, 0);
      acc[0][1] = __builtin_amdgcn_mfma_f32_16x16x32_bf16(a0, b1, acc[0][1], 0, 0, 0);
      acc[1][0] = __builtin_amdgcn_mfma_f32_16x16x32_bf16(a1, b0, acc[1][0], 0, 0, 0);
      acc[1][1] = __builtin_amdgcn_mfma_f32_16x16x32_bf16(a1, b1, acc[1][1], 0, 0, 0);
    }
    __syncthreads();
  }
  int lrow = (l >> 4) << 2, lcol = l & 15;
#pragma unroll
  for (int i = 0; i < 2; ++i)
#pragma unroll
    for (int j = 0; j < 2; ++j) {
      int c = col0 + wc + (j << 4) + lcol;
      int r0 = row0 + wr + (i << 4) + lrow;
#pragma unroll
      for (int rg = 0; rg < 4; ++rg)
        atomicAdd(&W2f[(size_t)(r0 + rg) * 1024 + c], acc[i][j][rg]);
    }
#pragma unroll
  for (int i = 0; i < 2; ++i)
#pragma unroll
    for (int rg = 0; rg < 4; ++rg) {
      float rs = acc[i][0][rg] + acc[i][1][rg];
#pragma unroll
      for (int o = 1; o < 16; o <<= 1) rs += __shfl_xor(rs, o, 64);
      if ((l & 15) == 0) {
        int r = row0 + wr + (i << 4) + lrow + rg;
        atomicAdd(&degsum2[r], rs);
      }
    }
}

__global__ __launch_bounds__(256) void fused_w2_g2a(
    const unsigned short* Wb, const unsigned short* WbT, const int* perm2, float* W2f,
    float* degsum2, const float* x1b, const unsigned short* t2T, const float* vals2,
    unsigned short* SAbT) {
  __shared__ char smem[16896];
  if (blockIdx.x < 1024) mm_w2_body(smem, blockIdx.x, Wb, WbT, perm2, W2f, degsum2);
  else gemm_e_body(smem, blockIdx.x - 1024, x1b, t2T, perm2, vals2, nullptr, 0,
                   nullptr, SAbT, 1024, 512, 512, 8);
}

// W2f -> W2Tb = ((W2 diag-zeroed + I) rows scaled by dinv2)^T bf16; emit dinv2
__global__ __launch_bounds__(256) void w2T(const float* __restrict__ W2f,
                                           const float* __restrict__ degsum2,
                                           unsigned short* __restrict__ W2Tb,
                                           float* __restrict__ dinv2v) {
  __shared__ float t[64][65];
  __shared__ float ds[64];
  int bx = blockIdx.x & 15, by = blockIdx.x >> 4;
  int r0 = by << 6, c0 = bx << 6;
  if (threadIdx.x < 64) {
    int r = r0 + threadIdx.x;
    float dg = degsum2[r] - W2f[(size_t)r * 1024 + r];  // exclude diag (exact ints)
    float dv = rsqrtf(dg + 1.f);
    ds[threadIdx.x] = dv;
    if (bx == 0) dinv2v[r] = dv;
  }
  for (int it = 0; it < 16; ++it) {
    int idx = (it << 8) + threadIdx.x;
    int r = idx >> 6, c = idx & 63;
    float v = W2f[(size_t)(r0 + r) * 1024 + c0 + c];
    if (r0 + r == c0 + c) v = 1.f;  // A2 = W2_diagzeroed + I
    t[r][c] = v;
  }
  __syncthreads();
  for (int it = 0; it < 16; ++it) {
    int idx = (it << 8) + threadIdx.x;
    int rr = idx >> 6, cc = idx & 63;
    W2Tb[(size_t)(c0 + rr) * 1024 + r0 + cc] = f2bf(t[cc][rr] * ds[cc]);
  }
}

// reduce + GCN epilogue (agg includes +I); optional scatter-add
__global__ __launch_bounds__(256) void epi_red1(const float* __restrict__ Pf,
                                                const float* __restrict__ dinv,
                                                const float* __restrict__ bias,
                                                const int* __restrict__ permS,
                                                float* __restrict__ scatterDst,
                                                float* __restrict__ outp, int M, int N) {
  int g = blockIdx.x * 256 + threadIdx.x;
  size_t base = (size_t)g * 4;
  size_t MN = (size_t)M * N;
  if (base >= MN) return;
  int r = (int)(base / N), c = (int)(base % N);
  float4 a = *(const float4*)&Pf[base];
#pragma unroll
  for (int s = 1; s < SPLITS; ++s) {
    float4 p = *(const float4*)&Pf[s * MN + base];
    a.x += p.x; a.y += p.y; a.z += p.z; a.w += p.w;
  }
  float dv = dinv[r];
  float4 bb = *(const float4*)&bias[c];
  float4 o;
  o.x = fmaxf(dv * a.x + bb.x, 0.f);
  o.y = fmaxf(dv * a.y + bb.y, 0.f);
  o.z = fmaxf(dv * a.z + bb.z, 0.f);
  o.w = fmaxf(dv * a.w + bb.w, 0.f);
  if (outp) *(float4*)&outp[base] = o;
  if (permS) {
    float4* d = (float4*)&scatterDst[(size_t)permS[r] * N + c];
    float4 cur = *d;
    cur.x += o.x; cur.y += o.y; cur.z += o.z; cur.w += o.w;
    *d = cur;
  }
}

// 4-slice reduce + relu + pool-2 score. M=2048, N=512. 2 rows/block.
__global__ __launch_bounds__(256) void epi_red1s(const float* __restrict__ Pf,
                                                 const float* __restrict__ dinv,
                                                 const float* __restrict__ bias,
                                                 const float* __restrict__ pvec,
                                                 float* __restrict__ sc,
                                                 float* __restrict__ outp) {
  __shared__ float shs[2][2][2];
  int li = threadIdx.x & 127;
  int lr = threadIdx.x >> 7;
  int r = blockIdx.x * 2 + lr;
  size_t base = (size_t)r * 512 + li * 4;
  const size_t MN = (size_t)2048 * 512;
  float4 a = *(const float4*)&Pf[base];
#pragma unroll
  for (int s = 1; s < SPLITS; ++s) {
    float4 p = *(const float4*)&Pf[s * MN + base];
    a.x += p.x; a.y += p.y; a.z += p.z; a.w += p.w;
  }
  float dv = dinv[r];
  float4 bb = *(const float4*)&bias[li * 4];
  float4 o;
  o.x = fmaxf(dv * a.x + bb.x, 0.f);
  o.y = fmaxf(dv * a.y + bb.y, 0.f);
  o.z = fmaxf(dv * a.z + bb.z, 0.f);
  o.w = fmaxf(dv * a.w + bb.w, 0.f);
  *(float4*)&outp[base] = o;
  float4 pv = *(const float4*)&pvec[li * 4];
  float s1 = pv.x * pv.x + pv.y * pv.y + pv.z * pv.z + pv.w * pv.w;
  float s2 = o.x * pv.x + o.y * pv.y + o.z * pv.z + o.w * pv.w;
#pragma unroll
  for (int t = 32; t > 0; t >>= 1) {
    s1 += __shfl_down(s1, t, 64);
    s2 += __shfl_down(s2, t, 64);
  }
  int wir = (threadIdx.x >> 6) & 1;
  if ((threadIdx.x & 63) == 0) { shs[lr][wir][0] = s1; shs[lr][wir][1] = s2; }
  __syncthreads();
  if ((threadIdx.x & 127) == 0) {
    float S1 = shs[lr][0][0] + shs[lr][1][0];
    float S2 = shs[lr][0][1] + shs[lr][1][1];
    sc[r] = tanhf(S2 / sqrtf(S1));
  }
}

// level-0 GCN epilogue + (optional) pool score. C=256: row == one wave.
template <int C, bool SCORE>
__global__ __launch_bounds__(256) void gcn_spmm4(const int* __restrict__ iptr,
                                                 const int* __restrict__ isrc,
                                                 const float* __restrict__ Z,
                                                 const float* __restrict__ dinv,
                                                 const float* __restrict__ bias,
                                                 const float* __restrict__ pvec,
                                                 float* __restrict__ sc,
                                                 float* __restrict__ outp) {
  constexpr int L = C / 4;
  int li = threadIdx.x % L;
  int i = blockIdx.x * (256 / L) + threadIdx.x / L;
  float4 acc = *(const float4*)(Z + (size_t)i * C + li * 4);
  int beg = iptr[i], end = iptr[i + 1];
  for (int e = beg; e < end; ++e) {
    float4 z = *(const float4*)(Z + (size_t)isrc[e] * C + li * 4);
    acc.x += z.x; acc.y += z.y; acc.z += z.z; acc.w += z.w;
  }
  float d = dinv[i];
  float4 bb = *(const float4*)(bias + li * 4);
  float4 o;
  o.x = fmaxf(d * acc.x + bb.x, 0.f);
  o.y = fmaxf(d * acc.y + bb.y, 0.f);
  o.z = fmaxf(d * acc.z + bb.z, 0.f);
  o.w = fmaxf(d * acc.w + bb.w, 0.f);
  *(float4*)(outp + (size_t)i * C + li * 4) = o;
  if (SCORE) {
    float4 pv = *(const float4*)(pvec + li * 4);
    float s1 = pv.x * pv.x + pv.y * pv.y + pv.z * pv.z + pv.w * pv.w;
    float s2 = o.x * pv.x + o.y * pv.y + o.z * pv.z + o.w * pv.w;
#pragma unroll
    for (int t = 32; t > 0; t >>= 1) {
      s1 += __shfl_down(s1, t, 64);
      s2 += __shfl_down(s2, t, 64);
    }
    if ((threadIdx.x & 63) == 0) sc[i] = tanhf(s2 / sqrtf(s1));
  }
}

// ---- top-k via radix select ----
__global__ __launch_bounds__(1024) void topk_select(const float* __restrict__ score,
                                                    int n, int k, int* __restrict__ perm,
                                                    float* __restrict__ vals,
                                                    int* __restrict__ rank) {
  __shared__ unsigned int keys[4096];
  __shared__ int hist[256];
  __shared__ int wsums[16];
  __shared__ unsigned int sh_prefix;
  __shared__ int sh_rem;
  int t = threadIdx.x;
  int m = n >> 10;
  for (int i = t; i < n; i += 1024) {
    unsigned int u = __float_as_uint(score[i]);
    keys[i] = u ^ ((unsigned int)((int)u >> 31) | 0x80000000u);
  }
  if (t == 0) { sh_prefix = 0u; sh_rem = k; }
  __syncthreads();
  for (int round = 0; round < 4; ++round) {
    int shift = 24 - (round << 3);
    if (t < 256) hist[t] = 0;
    __syncthreads();
    unsigned int prefix = sh_prefix;
    unsigned int maskhi = (round == 0) ? 0u : (0xFFFFFFFFu << (shift + 8));
    for (int i = t; i < n; i += 1024) {
      unsigned int kk = keys[i];
      if ((kk & maskhi) == prefix) atomicAdd(&hist[(kk >> shift) & 255], 1);
    }
    __syncthreads();
    if (t == 0) {
      int rem = sh_rem, acc = 0, b = 255;
      for (; b > 0; --b) {
        if (acc + hist[b] >= rem) break;
        acc += hist[b];
      }
      sh_rem = rem - acc;
      sh_prefix = prefix | ((unsigned int)b << shift);
    }
    __syncthreads();
  }
  unsigned int thr = sh_prefix;
  int need = sh_rem;
  int base = t * m;
  int f[4];
  int cnt = 0;
#pragma unroll
  for (int j = 0; j < 4; ++j) {
    f[j] = 0;
    if (j < m) { f[j] = (keys[base + j] == thr) ? 1 : 0; cnt += f[j]; }
  }
  int ex = blockScanExclusive(cnt, wsums);
  int sel[4];
  int scnt = 0;
#pragma unroll
  for (int j = 0; j < 4; ++j) {
    sel[j] = 0;
    if (j < m) {
      unsigned int kk = keys[base + j];
      sel[j] = (kk > thr) || (kk == thr && ex < need);
      ex += f[j];
      scnt += sel[j];
    }
  }
  int pos = blockScanExclusive(scnt, wsums);
#pragma unroll
  for (int j = 0; j < 4; ++j) {
    if (j < m) {
      int i = base + j;
      if (sel[j]) {
        unsigned int kk = keys[i];
        unsigned int u = (kk & 0x80000000u) ? (kk ^ 0x80000000u) : ~kk;
        perm[pos] = i;
        vals[pos] = __uint_as_float(u);
        rank[i] = pos;
        pos++;
      } else {
        rank[i] = -1;
      }
    }
  }
}

// A1[a,b] = W1+I (bf16, integer-exact, diag=1) + dinv1; wave-parallel
__global__ __launch_bounds__(256) void build_W1(const int* __restrict__ optr,
                                                const int* __restrict__ odst,
                                                const int* __restrict__ perm1,
                                                const int* __restrict__ rank1,
                                                unsigned short* __restrict__ W1b,
                                                float* __restrict__ dinv1) {
  __shared__ float row[2048];
  int a = blockIdx.x;
  int pa = perm1[a];
  for (int i = threadIdx.x; i < 2048; i += 256) row[i] = 0.f;
  __syncthreads();
  int kbeg = optr[pa], kend = optr[pa + 1];
  int nk = kend - kbeg + 1;
  int wv = threadIdx.x >> 6, lane = threadIdx.x & 63;
  for (int kidx = wv; kidx < nk; kidx += 4) {
    int k = (kidx == 0) ? pa : odst[kbeg + kidx - 1];
    int jbeg = optr[k], jend = optr[k + 1];
    for (int jj = jbeg - 1 + lane; jj < jend; jj += 64) {
      int j = (jj < jbeg) ? k : odst[jj];
      int rb = rank1[j];
      if (rb >= 0) atomicAdd(&row[rb], 1.0f);
    }
  }
  __syncthreads();
  float ssum = 0.f;
  for (int i = threadIdx.x; i < 2048; i += 256) {
    float v = row[i];
    W1b[(size_t)a * 2048 + i] = f2bf((i == a) ? 1.f : v);  // A1 = W1_offdiag + I
    ssum += (i == a) ? 0.f : v;
  }
  float t = blockReduceSum256(ssum);
  if (threadIdx.x == 0) dinv1[a] = rsqrtf(t + 1.0f);
}

__device__ void mean_cols_body(int c, const float* __restrict__ X, int R, int C,
                               float* __restrict__ outp) {
  float s = 0.f;
  for (int r = threadIdx.x; r < R; r += 256) s += X[(size_t)r * C + c];
  float t = blockReduceSum256(s);
  if (threadIdx.x == 0) outp[c] = t / (float)R;
}

__global__ __launch_bounds__(256) void fused_mean_up1a(
    const float* xb, float* meanOut, const float* x1b, const unsigned short* t3T,
    const float* dinv1, unsigned short* SAbT) {
  __shared__ char smem[16640];
  if (blockIdx.x < 512) mean_cols_body(blockIdx.x, xb, 1024, 512, meanOut);
  else gemm_e_body(smem, blockIdx.x - 512, x1b, t3T, nullptr, nullptr, dinv1, 1,
                   nullptr, SAbT, 2048, 256, 512, 4);
}

// ---------------- launcher ----------------
extern "C" void kernel_launch(void* const* d_in, const int* in_sizes, int n_in,
                              void* d_out, int out_size, void* d_ws, size_t ws_size,
                              hipStream_t stream) {
  const float* x      = (const float*)d_in[0];
  const int*   eidx   = (const int*)d_in[1];
  const float* theta0 = (const float*)d_in[2];
  const float* b0     = (const float*)d_in[3];
  const float* theta1 = (const float*)d_in[4];
  const float* b1     = (const float*)d_in[5];
  const float* theta2 = (const float*)d_in[6];
  const float* b2     = (const float*)d_in[7];
  const float* theta3 = (const float*)d_in[8];
  const float* b3     = (const float*)d_in[9];
  const float* theta4 = (const float*)d_in[10];
  const float* b4     = (const float*)d_in[11];
  const float* p1     = (const float*)d_in[12];
  const float* p2     = (const float*)d_in[13];
  const int E = in_sizes[1] / 2;
  const int* src = eidx;
  const int* dst = eidx + E;
  float* out = (float*)d_out;

  char* wsb = (char*)d_ws;
  size_t off = 0;
  auto alloc = [&](size_t bytes) -> void* {
    void* p = wsb + off;
    off = (off + bytes + 255) & ~(size_t)255;
    return p;
  };
  // zero-init block: cnt4 | degsum2 | W2f  (one memset)
  char* zblock = (char*)alloc((size_t)4 * N0 * 4 + P2K * 4 + (size_t)P2K * P2K * 4);
  int* cnt4 = (int*)zblock;
  float* degsum2 = (float*)(zblock + (size_t)4 * N0 * 4);
  float* W2f = (float*)(zblock + (size_t)4 * N0 * 4 + P2K * 4);
  size_t zbytes = (size_t)4 * N0 * 4 + P2K * 4 + (size_t)P2K * P2K * 4;

  int* optr  = (int*)alloc((N0 + 1) * 4);
  int* iptr  = (int*)alloc((N0 + 1) * 4);
  int* odst  = (int*)alloc((size_t)E * 4);
  int* isrc  = (int*)alloc((size_t)E * 4);
  int* perm1 = (int*)alloc(P1K * 4);
  int* rank1 = (int*)alloc(N0 * 4);
  int* perm2 = (int*)alloc(P2K * 4);
  int* rank2 = (int*)alloc(P1K * 4);
  float* dinv0 = (float*)alloc(N0 * 4);
  float* dinv1 = (float*)alloc(P1K * 4);
  float* dinv2v = (float*)alloc(P2K * 4);
  float* vals1 = (float*)alloc(P1K * 4);
  float* vals2 = (float*)alloc(P2K * 4);
  float* score = (float*)alloc(N0 * 4);
  float* x0  = (float*)alloc((size_t)N0 * 256 * 4);
  float* x1b = (float*)alloc((size_t)P1K * 512 * 4);
  float* xb  = (float*)alloc((size_t)P2K * 512 * 4);
  float* SA  = (float*)alloc((size_t)P1K * 512 * 4);        // Z scratch fp32
  float* Pf  = (float*)alloc((size_t)SPLITS * 1048576 * 4); // split-K partials (16 MB)
  unsigned short* W1b  = (unsigned short*)alloc((size_t)P1K * P1K * 2);
  unsigned short* W1bT = (unsigned short*)alloc((size_t)P1K * P1K * 2);
  unsigned short* W2Tb = (unsigned short*)alloc((size_t)P2K * P2K * 2);
  unsigned short* SAbT = (unsigned short*)alloc((size_t)524288 * 2);
  unsigned short* ZhT  = (unsigned short*)alloc((size_t)512 * 2048 * 2);
  unsigned short* ZlT  = (unsigned short*)alloc((size_t)512 * 2048 * 2);
  unsigned short* t0hT = (unsigned short*)alloc((size_t)256 * 128 * 2);
  unsigned short* t0lT = (unsigned short*)alloc((size_t)256 * 128 * 2);
  unsigned short* t1hT = (unsigned short*)alloc((size_t)512 * 256 * 2);
  unsigned short* t1lT = (unsigned short*)alloc((size_t)512 * 256 * 2);
  unsigned short* t2T  = (unsigned short*)alloc((size_t)512 * 512 * 2);
  unsigned short* t3T  = (unsigned short*)alloc((size_t)256 * 512 * 2);
  unsigned short* t4T  = (unsigned short*)alloc((size_t)128 * 256 * 2);
  (void)ws_size; (void)n_in; (void)out_size;

  int* co = cnt4;
  int* ci = cnt4 + N0;
  int* fo = cnt4 + 2 * N0;
  int* fi = cnt4 + 3 * N0;

  // --- graph build (count_edges || weight transposes) ---
  hipMemsetAsync(zblock, 0, zbytes, stream);
  fused_ce_conv<<<512 + 2304, 256, 0, stream>>>(src, dst, co, ci, E, theta0, theta1,
                                                theta2, theta3, theta4, t0hT, t0lT,
                                                t1hT, t1lT, t2T, t3T, t4T);
  exscan_dual<<<2, 1024, 0, stream>>>(co, ci, optr, iptr, dinv0);
  // fill_edges || gcn0 feature GEMM
  fused_fill_g3<<<512 + 256, 256, 0, stream>>>(src, dst, optr, iptr, fo, fi, odst, isrc,
                                               E, x, t0hT, t0lT, dinv0, SA);
  gcn_spmm4<256, true><<<1024, 256, 0, stream>>>(iptr, isrc, SA, dinv0, b0, p1, score, x0);

  // --- pool 1 ---
  topk_select<<<1, 1024, 0, stream>>>(score, 4096, 2048, perm1, vals1, rank1);
  build_W1<<<2048, 256, 0, stream>>>(optr, odst, perm1, rank1, W1b, dinv1);
  // A1 transpose || gcn1 feature GEMM
  fused_tr_g3<<<1024 + 256, 256, 0, stream>>>(W1b, W1bT, x0, t1hT, t1lT, perm1, vals1,
                                              dinv1, ZhT, ZlT);

  // --- gcn1 aggregation: A1^T (Zh+Zl) (+I folded) + pool-2 scores ---
  gemm_skd<<<256 * SPLITS, 256, 0, stream>>>(W1bT, ZhT, ZlT, Pf, 2048, 512, 2048, 8, 256);
  epi_red1s<<<1024, 256, 0, stream>>>(Pf, dinv1, b1, p2, score, x1b);

  // --- pool 2 ---
  topk_select<<<1, 1024, 0, stream>>>(score, 2048, 1024, perm2, vals2, rank2);
  // W2 build (+row sums) || gcn2 feature GEMM (Y bf16^T only)
  fused_w2_g2a<<<1024 + 128, 256, 0, stream>>>(W1b, W1bT, perm2, W2f, degsum2, x1b, t2T,
                                               vals2, SAbT);
  w2T<<<256, 256, 0, stream>>>(W2f, degsum2, W2Tb, dinv2v);

  // --- gcn2 aggregation: (A2 dinv2)^T Y; epilogue scatters into x1b ---
  gemm_sk<<<128 * SPLITS, 256, 0, stream>>>(W2Tb, SAbT, Pf, 1024, 512, 1024, 8, 128);
  epi_red1<<<1024 * 512 / 1024, 256, 0, stream>>>(Pf, dinv2v, b2, perm2, x1b, xb,
                                                  1024, 512);
  // summary mean || up1 feature GEMM
  fused_mean_up1a<<<512 + 128, 256, 0, stream>>>(xb, out + 524288, x1b, t3T, dinv1, SAbT);

  // --- up block 1: A1^T Z3 (+I folded); epilogue scatters into x0 ---
  gemm_sk<<<128 * SPLITS, 256, 0, stream>>>(W1bT, SAbT, Pf, 2048, 256, 2048, 4, 128);
  epi_red1<<<2048 * 256 / 1024, 256, 0, stream>>>(Pf, dinv1, b3, perm1, x0, nullptr,
                                                  2048, 256);

  // --- up block 0: feature GEMM + fp32 sparse agg -> out ---
  gemm_e_k<<<128, 256, 0, stream>>>(x0, t4T, nullptr, nullptr, dinv0, 1, SA, nullptr,
                                    4096, 128, 256, 2);
  gcn_spmm4<128, false><<<512, 256, 0, stream>>>(iptr, isrc, SA, dinv0, b4, nullptr,
                                                 nullptr, out);
}

// Round 14
// 293.900 us; speedup vs baseline: 1.1423x; 1.0301x over previous
//
#include <hip/hip_runtime.h>

#define N0 4096
#define P1K 2048
#define P2K 1024
#define SPLITS 4

typedef short bf16x8 __attribute__((ext_vector_type(8)));
typedef float f32x4 __attribute__((ext_vector_type(4)));

__device__ __forceinline__ unsigned short f2bf(float f) {
  unsigned int u = __float_as_uint(f);
  unsigned int r = (u + 0x7fff + ((u >> 16) & 1)) >> 16;
  return (unsigned short)r;
}
__device__ __forceinline__ float bf2f(unsigned short h) {
  unsigned int u = ((unsigned int)h) << 16;
  return __uint_as_float(u);
}

// ---------------- helpers ----------------
__device__ __forceinline__ float blockReduceSum256(float v) {
  __shared__ float sh[16];
  int lane = threadIdx.x & 63;
  int w = threadIdx.x >> 6;
#pragma unroll
  for (int o = 32; o > 0; o >>= 1) v += __shfl_down(v, o, 64);
  __syncthreads();
  if (lane == 0) sh[w] = v;
  __syncthreads();
  float r = 0.f;
  if (threadIdx.x == 0) {
    int nw = (blockDim.x + 63) >> 6;
    for (int i = 0; i < nw; ++i) r += sh[i];
  }
  return r;  // valid on thread 0 only
}

__device__ __forceinline__ int blockScanExclusive(int v, volatile int* wsums) {
  int lane = threadIdx.x & 63, w = threadIdx.x >> 6;
  int x = v;
#pragma unroll
  for (int o = 1; o < 64; o <<= 1) {
    int y = __shfl_up(x, o, 64);
    if (lane >= o) x += y;
  }
  if (lane == 63) wsums[w] = x;
  __syncthreads();
  if (threadIdx.x < 64) {
    int nw = blockDim.x >> 6;
    int s = (threadIdx.x < nw) ? wsums[threadIdx.x] : 0;
#pragma unroll
    for (int o = 1; o < 16; o <<= 1) {
      int y = __shfl_up(s, o, 64);
      if (lane >= o) s += y;
    }
    if (threadIdx.x < nw) wsums[threadIdx.x] = s;
  }
  __syncthreads();
  int base = (w > 0) ? wsums[w - 1] : 0;
  __syncthreads();
  return base + x - v;
}

// ---------------- graph build bodies ----------------
__device__ __forceinline__ void count_edges_body(int b, const int* __restrict__ src,
                                                 const int* __restrict__ dst,
                                                 int* __restrict__ co, int* __restrict__ ci,
                                                 int E) {
  int e = b * 256 + threadIdx.x;
  if (e < E) {
    atomicAdd(&co[src[e]], 1);
    atomicAdd(&ci[dst[e]], 1);
  }
}

__device__ __forceinline__ void conv_body(int b, const float* __restrict__ t0,
                                          const float* __restrict__ t1,
                                          const float* __restrict__ t2,
                                          const float* __restrict__ t3,
                                          const float* __restrict__ t4,
                                          unsigned short* __restrict__ o0h,
                                          unsigned short* __restrict__ o0l,
                                          unsigned short* __restrict__ o1h,
                                          unsigned short* __restrict__ o1l,
                                          unsigned short* __restrict__ o2,
                                          unsigned short* __restrict__ o3,
                                          unsigned short* __restrict__ o4) {
  int idx = b * 256 + threadIdx.x;
  if (idx < 32768) {
    int k = idx >> 8, n = idx & 255;
    float v = t0[idx];
    unsigned short h = f2bf(v);
    o0h[(size_t)n * 128 + k] = h;
    o0l[(size_t)n * 128 + k] = f2bf(v - bf2f(h));
  } else if (idx < 163840) {
    int i = idx - 32768;
    int k = i >> 9, n = i & 511;
    float v = t1[i];
    unsigned short h = f2bf(v);
    o1h[(size_t)n * 256 + k] = h;
    o1l[(size_t)n * 256 + k] = f2bf(v - bf2f(h));
  } else if (idx < 425984) {
    int i = idx - 163840;
    int k = i >> 9, n = i & 511;
    o2[(size_t)n * 512 + k] = f2bf(t2[i]);
  } else if (idx < 557056) {
    int i = idx - 425984;
    int k = i >> 8, n = i & 255;
    o3[(size_t)n * 512 + k] = f2bf(t3[i]);
  } else if (idx < 589824) {
    int i = idx - 557056;
    int k = i >> 7, n = i & 127;
    o4[(size_t)n * 256 + k] = f2bf(t4[i]);
  }
}

__global__ __launch_bounds__(256) void fused_ce_conv(
    const int* __restrict__ src, const int* __restrict__ dst, int* __restrict__ co,
    int* __restrict__ ci, int E, const float* t0, const float* t1, const float* t2,
    const float* t3, const float* t4, unsigned short* o0h, unsigned short* o0l,
    unsigned short* o1h, unsigned short* o1l, unsigned short* o2, unsigned short* o3,
    unsigned short* o4) {
  if (blockIdx.x < 512) count_edges_body(blockIdx.x, src, dst, co, ci, E);
  else conv_body(blockIdx.x - 512, t0, t1, t2, t3, t4, o0h, o0l, o1h, o1l, o2, o3, o4);
}

// block 0: co->optr (+dinv0), block 1: ci->iptr
__global__ __launch_bounds__(1024) void exscan_dual(const int* __restrict__ co,
                                                    const int* __restrict__ ci,
                                                    int* __restrict__ optr,
                                                    int* __restrict__ iptr,
                                                    float* __restrict__ dinv0) {
  __shared__ int ls[1024];
  const int* cnt = blockIdx.x ? ci : co;
  int* ptr = blockIdx.x ? iptr : optr;
  int t = threadIdx.x;
  int v0 = cnt[t * 4], v1 = cnt[t * 4 + 1], v2 = cnt[t * 4 + 2], v3 = cnt[t * 4 + 3];
  int s = v0 + v1 + v2 + v3;
  ls[t] = s;
  __syncthreads();
  for (int off = 1; off < 1024; off <<= 1) {
    int x = (t >= off) ? ls[t - off] : 0;
    __syncthreads();
    ls[t] += x;
    __syncthreads();
  }
  int ex = (t > 0) ? ls[t - 1] : 0;
  ptr[t * 4]     = ex;
  ptr[t * 4 + 1] = ex + v0;
  ptr[t * 4 + 2] = ex + v0 + v1;
  ptr[t * 4 + 3] = ex + v0 + v1 + v2;
  if (t == 1023) ptr[4096] = ex + s;
  if (blockIdx.x == 0) {
    dinv0[t * 4]     = rsqrtf((float)v0 + 1.f);
    dinv0[t * 4 + 1] = rsqrtf((float)v1 + 1.f);
    dinv0[t * 4 + 2] = rsqrtf((float)v2 + 1.f);
    dinv0[t * 4 + 3] = rsqrtf((float)v3 + 1.f);
  }
}

__device__ __forceinline__ void fill_body(int b, const int* __restrict__ src,
                                          const int* __restrict__ dst,
                                          const int* __restrict__ optr,
                                          const int* __restrict__ iptr,
                                          int* __restrict__ fo, int* __restrict__ fi,
                                          int* __restrict__ odst, int* __restrict__ isrc,
                                          int E) {
  int e = b * 256 + threadIdx.x;
  if (e < E) {
    int s = src[e], d = dst[e];
    odst[optr[s] + atomicAdd(&fo[s], 1)] = d;
    isrc[iptr[d] + atomicAdd(&fi[d], 1)] = s;
  }
}

// ---- fp32-emulated MFMA GEMM (3-term bf16 split) body; smem: 32768 B ----
template <bool TOUT>
__device__ void gemm3_body(char* smem, int bid, const float* __restrict__ A,
                           const unsigned short* __restrict__ BhT,
                           const unsigned short* __restrict__ BlT,
                           const int* __restrict__ permA, const float* __restrict__ valsA,
                           const float* __restrict__ dinv, float* __restrict__ C,
                           unsigned short* __restrict__ ChT, unsigned short* __restrict__ ClT,
                           int M, int N, int K, int nbx) {
  unsigned short* U = (unsigned short*)smem;
  unsigned short* Ah = U;
  unsigned short* Al = U + 4096;
  unsigned short* Bh = U + 8192;
  unsigned short* Bl = U + 12288;
  int tid = threadIdx.x;
  int by = bid / nbx, bx = bid % nbx;
  int row0 = by << 6, col0 = bx << 6;
  int l = tid & 63, wv = tid >> 6;
  int wr = (wv >> 1) << 5, wc = (wv & 1) << 5;
  f32x4 acc[2][2] = {};
  for (int k0 = 0; k0 < K; k0 += 64) {
#pragma unroll
    for (int it = 0; it < 2; ++it) {
      int idx = (it << 8) + tid;
      int r = idx >> 3, c8 = idx & 7;
      int sw = c8 ^ (r & 7);
      int row = row0 + r;
      int srow = permA ? permA[row] : row;
      float vs = valsA ? valsA[row] : 1.f;
      const float* Af = A + (size_t)srow * K + k0 + (c8 << 3);
      float4 f0 = *(const float4*)Af;
      float4 f1 = *(const float4*)(Af + 4);
      float vv[8] = {f0.x * vs, f0.y * vs, f0.z * vs, f0.w * vs,
                     f1.x * vs, f1.y * vs, f1.z * vs, f1.w * vs};
      uint4 uh, ul;
      unsigned short hh[8], ll[8];
#pragma unroll
      for (int q = 0; q < 8; ++q) {
        hh[q] = f2bf(vv[q]);
        ll[q] = f2bf(vv[q] - bf2f(hh[q]));
      }
      uh.x = (unsigned)hh[0] | ((unsigned)hh[1] << 16);
      uh.y = (unsigned)hh[2] | ((unsigned)hh[3] << 16);
      uh.z = (unsigned)hh[4] | ((unsigned)hh[5] << 16);
      uh.w = (unsigned)hh[6] | ((unsigned)hh[7] << 16);
      ul.x = (unsigned)ll[0] | ((unsigned)ll[1] << 16);
      ul.y = (unsigned)ll[2] | ((unsigned)ll[3] << 16);
      ul.z = (unsigned)ll[4] | ((unsigned)ll[5] << 16);
      ul.w = (unsigned)ll[6] | ((unsigned)ll[7] << 16);
      ((uint4*)Ah)[(r << 3) + sw] = uh;
      ((uint4*)Al)[(r << 3) + sw] = ul;
      ((uint4*)Bh)[(r << 3) + sw] =
          *(const uint4*)(BhT + (size_t)(col0 + r) * K + k0 + (c8 << 3));
      ((uint4*)Bl)[(r << 3) + sw] =
          *(const uint4*)(BlT + (size_t)(col0 + r) * K + k0 + (c8 << 3));
    }
    __syncthreads();
#pragma unroll
    for (int kk2 = 0; kk2 < 2; ++kk2) {
      int ch = (kk2 << 2) + (l >> 4);
      int ra = wr + (l & 15), rb = ra + 16;
      int ca = wc + (l & 15), cb = ca + 16;
      int oa0 = (ra << 6) + ((ch ^ (ra & 7)) << 3);
      int oa1 = (rb << 6) + ((ch ^ (rb & 7)) << 3);
      int ob0 = (ca << 6) + ((ch ^ (ca & 7)) << 3);
      int ob1 = (cb << 6) + ((ch ^ (cb & 7)) << 3);
      bf16x8 ah0 = *(const bf16x8*)&Ah[oa0], ah1 = *(const bf16x8*)&Ah[oa1];
      bf16x8 al0 = *(const bf16x8*)&Al[oa0], al1 = *(const bf16x8*)&Al[oa1];
      bf16x8 bh0 = *(const bf16x8*)&Bh[ob0], bh1 = *(const bf16x8*)&Bh[ob1];
      bf16x8 bl0 = *(const bf16x8*)&Bl[ob0], bl1 = *(const bf16x8*)&Bl[ob1];
      acc[0][0] = __builtin_amdgcn_mfma_f32_16x16x32_bf16(ah0, bh0, acc[0][0], 0, 0, 0);
      acc[0][1] = __builtin_amdgcn_mfma_f32_16x16x32_bf16(ah0, bh1, acc[0][1], 0, 0, 0);
      acc[1][0] = __builtin_amdgcn_mfma_f32_16x16x32_bf16(ah1, bh0, acc[1][0], 0, 0, 0);
      acc[1][1] = __builtin_amdgcn_mfma_f32_16x16x32_bf16(ah1, bh1, acc[1][1], 0, 0, 0);
      acc[0][0] = __builtin_amdgcn_mfma_f32_16x16x32_bf16(ah0, bl0, acc[0][0], 0, 0, 0);
      acc[0][1] = __builtin_amdgcn_mfma_f32_16x16x32_bf16(ah0, bl1, acc[0][1], 0, 0, 0);
      acc[1][0] = __builtin_amdgcn_mfma_f32_16x16x32_bf16(ah1, bl0, acc[1][0], 0, 0, 0);
      acc[1][1] = __builtin_amdgcn_mfma_f32_16x16x32_bf16(ah1, bl1, acc[1][1], 0, 0, 0);
      acc[0][0] = __builtin_amdgcn_mfma_f32_16x16x32_bf16(al0, bh0, acc[0][0], 0, 0, 0);
      acc[0][1] = __builtin_amdgcn_mfma_f32_16x16x32_bf16(al0, bh1, acc[0][1], 0, 0, 0);
      acc[1][0] = __builtin_amdgcn_mfma_f32_16x16x32_bf16(al1, bh0, acc[1][0], 0, 0, 0);
      acc[1][1] = __builtin_amdgcn_mfma_f32_16x16x32_bf16(al1, bh1, acc[1][1], 0, 0, 0);
    }
    __syncthreads();
  }
  int lrow = (l >> 4) << 2, lcol = l & 15;
  float* tf = (float*)smem;
#pragma unroll
  for (int i = 0; i < 2; ++i)
#pragma unroll
    for (int j = 0; j < 2; ++j) {
      int lc = wc + (j << 4) + lcol;
      int lr0 = wr + (i << 4) + lrow;
      int c = col0 + lc;
#pragma unroll
      for (int rg = 0; rg < 4; ++rg) {
        int lr = lr0 + rg;
        int r = row0 + lr;
        float dv = dinv ? dinv[r] : 1.f;
        float v = acc[i][j][rg] * dv;
        if (C) C[(size_t)r * N + c] = v;
        if (TOUT) tf[lr * 65 + lc] = v;
      }
    }
  if (TOUT) {
    __syncthreads();
    for (int it = 0; it < 16; ++it) {
      int idx = (it << 8) + tid;
      int rr = idx >> 6, cc = idx & 63;
      float v = tf[cc * 65 + rr];
      unsigned short h = f2bf(v);
      size_t o = (size_t)(col0 + rr) * M + row0 + cc;
      ChT[o] = h;
      ClT[o] = f2bf(v - bf2f(h));
    }
  }
}

__global__ __launch_bounds__(256) void fused_fill_g3(
    const int* src, const int* dst, const int* optr, const int* iptr, int* fo, int* fi,
    int* odst, int* isrc, int E, const float* x, const unsigned short* t0hT,
    const unsigned short* t0lT, const float* dinv0, float* SA) {
  __shared__ char smem[32768];
  if (blockIdx.x < 512) fill_body(blockIdx.x, src, dst, optr, iptr, fo, fi, odst, isrc, E);
  else gemm3_body<false>(smem, blockIdx.x - 512, x, t0hT, t0lT, nullptr, nullptr, dinv0,
                         SA, nullptr, nullptr, 4096, 256, 128, 4);
}

// ---- 64x64-tile bf16 transpose body ----
__device__ void transpose_body(char* smem, int bid, const unsigned short* __restrict__ in,
                               unsigned short* __restrict__ out, int n) {
  unsigned short* t = (unsigned short*)smem;  // [64][65]
  int nb = n >> 6;
  int bx = bid % nb, by = bid / nb;
  int r0 = by << 6, c0 = bx << 6;
  for (int it = 0; it < 16; ++it) {
    int idx = (it << 8) + threadIdx.x;
    int r = idx >> 6, c = idx & 63;
    t[r * 65 + c] = in[(size_t)(r0 + r) * n + c0 + c];
  }
  __syncthreads();
  for (int it = 0; it < 16; ++it) {
    int idx = (it << 8) + threadIdx.x;
    int r = idx >> 6, c = idx & 63;
    out[(size_t)(c0 + r) * n + r0 + c] = t[c * 65 + r];
  }
}

__global__ __launch_bounds__(256) void fused_tr_g3(
    const unsigned short* W1b, unsigned short* W1bT, const float* x0,
    const unsigned short* t1hT, const unsigned short* t1lT, const int* perm1,
    const float* vals1, const float* dinv1, unsigned short* ZhT, unsigned short* ZlT) {
  __shared__ char smem[32768];
  if (blockIdx.x < 1024) transpose_body(smem, blockIdx.x, W1b, W1bT, 2048);
  else gemm3_body<true>(smem, blockIdx.x - 1024, x0, t1hT, t1lT, perm1, vals1, dinv1,
                        nullptr, ZhT, ZlT, 2048, 512, 256, 8);
}

// ---- dual-B split-K GEMM: Pf[s] = A @ (Bh + Bl) (gcn1: A1^T (Zh+Zl)) ----
__global__ __launch_bounds__(256) void gemm_skd(const unsigned short* __restrict__ A,
                                                const unsigned short* __restrict__ BhT,
                                                const unsigned short* __restrict__ BlT,
                                                float* __restrict__ Pf,
                                                int M, int N, int K, int nbx, int nb2d) {
  __shared__ unsigned short As[4096], Bh[4096], Bl[4096];
  int tid = threadIdx.x;
  int s = blockIdx.x / nb2d;
  int r2 = blockIdx.x % nb2d;
  int by = r2 / nbx, bx = r2 % nbx;
  int row0 = by << 6, col0 = bx << 6;
  int kc = K / SPLITS;
  int ks = s * kc, ke = ks + kc;
  int l = tid & 63, wv = tid >> 6;
  int wr = (wv >> 1) << 5, wc = (wv & 1) << 5;
  f32x4 acc[2][2] = {};
  for (int k0 = ks; k0 < ke; k0 += 64) {
#pragma unroll
    for (int it = 0; it < 2; ++it) {
      int idx = (it << 8) + tid;
      int r = idx >> 3, c8 = idx & 7;
      int sw = c8 ^ (r & 7);
      ((uint4*)As)[(r << 3) + sw] =
          *(const uint4*)(A + (size_t)(row0 + r) * K + k0 + (c8 << 3));
      ((uint4*)Bh)[(r << 3) + sw] =
          *(const uint4*)(BhT + (size_t)(col0 + r) * K + k0 + (c8 << 3));
      ((uint4*)Bl)[(r << 3) + sw] =
          *(const uint4*)(BlT + (size_t)(col0 + r) * K + k0 + (c8 << 3));
    }
    __syncthreads();
#pragma unroll
    for (int kk2 = 0; kk2 < 2; ++kk2) {
      int ch = (kk2 << 2) + (l >> 4);
      int ra = wr + (l & 15), rb = ra + 16;
      int ca = wc + (l & 15), cb = ca + 16;
      bf16x8 a0 = *(const bf16x8*)&As[(ra << 6) + ((ch ^ (ra & 7)) << 3)];
      bf16x8 a1 = *(const bf16x8*)&As[(rb << 6) + ((ch ^ (rb & 7)) << 3)];
      bf16x8 bh0 = *(const bf16x8*)&Bh[(ca << 6) + ((ch ^ (ca & 7)) << 3)];
      bf16x8 bh1 = *(const bf16x8*)&Bh[(cb << 6) + ((ch ^ (cb & 7)) << 3)];
      bf16x8 bl0 = *(const bf16x8*)&Bl[(ca << 6) + ((ch ^ (ca & 7)) << 3)];
      bf16x8 bl1 = *(const bf16x8*)&Bl[(cb << 6) + ((ch ^ (cb & 7)) << 3)];
      acc[0][0] = __builtin_amdgcn_mfma_f32_16x16x32_bf16(a0, bh0, acc[0][0], 0, 0, 0);
      acc[0][1] = __builtin_amdgcn_mfma_f32_16x16x32_bf16(a0, bh1, acc[0][1], 0, 0, 0);
      acc[1][0] = __builtin_amdgcn_mfma_f32_16x16x32_bf16(a1, bh0, acc[1][0], 0, 0, 0);
      acc[1][1] = __builtin_amdgcn_mfma_f32_16x16x32_bf16(a1, bh1, acc[1][1], 0, 0, 0);
      acc[0][0] = __builtin_amdgcn_mfma_f32_16x16x32_bf16(a0, bl0, acc[0][0], 0, 0, 0);
      acc[0][1] = __builtin_amdgcn_mfma_f32_16x16x32_bf16(a0, bl1, acc[0][1], 0, 0, 0);
      acc[1][0] = __builtin_amdgcn_mfma_f32_16x16x32_bf16(a1, bl0, acc[1][0], 0, 0, 0);
      acc[1][1] = __builtin_amdgcn_mfma_f32_16x16x32_bf16(a1, bl1, acc[1][1], 0, 0, 0);
    }
    __syncthreads();
  }
  int lrow = (l >> 4) << 2, lcol = l & 15;
  float* P = Pf + (size_t)s * M * N;
#pragma unroll
  for (int i = 0; i < 2; ++i)
#pragma unroll
    for (int j = 0; j < 2; ++j) {
      int c = col0 + wc + (j << 4) + lcol;
      int r0 = row0 + wr + (i << 4) + lrow;
#pragma unroll
      for (int rg = 0; rg < 4; ++rg)
        P[(size_t)(r0 + rg) * N + c] = acc[i][j][rg];
    }
}

// ---- split-K bf16 MFMA GEMM (A bf16) ----
__global__ __launch_bounds__(256) void gemm_sk(const unsigned short* __restrict__ A,
                                               const unsigned short* __restrict__ BT,
                                               float* __restrict__ Pf,
                                               int M, int N, int K, int nbx, int nb2d) {
  __shared__ unsigned short As[4096];
  __shared__ unsigned short Bs[4096];
  int tid = threadIdx.x;
  int s = blockIdx.x / nb2d;
  int r2 = blockIdx.x % nb2d;
  int by = r2 / nbx, bx = r2 % nbx;
  int row0 = by << 6, col0 = bx << 6;
  int kc = K / SPLITS;
  int ks = s * kc, ke = ks + kc;
  int l = tid & 63, wv = tid >> 6;
  int wr = (wv >> 1) << 5, wc = (wv & 1) << 5;
  f32x4 acc[2][2] = {};
  for (int k0 = ks; k0 < ke; k0 += 64) {
#pragma unroll
    for (int it = 0; it < 2; ++it) {
      int idx = (it << 8) + tid;
      int r = idx >> 3, c8 = idx & 7;
      int sw = c8 ^ (r & 7);
      ((uint4*)As)[(r << 3) + sw] =
          *(const uint4*)(A + (size_t)(row0 + r) * K + k0 + (c8 << 3));
      ((uint4*)Bs)[(r << 3) + sw] =
          *(const uint4*)(BT + (size_t)(col0 + r) * K + k0 + (c8 << 3));
    }
    __syncthreads();
#pragma unroll
    for (int kk2 = 0; kk2 < 2; ++kk2) {
      int ch = (kk2 << 2) + (l >> 4);
      int ra = wr + (l & 15), rb = ra + 16;
      int ca = wc + (l & 15), cb = ca + 16;
      bf16x8 a0 = *(const bf16x8*)&As[(ra << 6) + ((ch ^ (ra & 7)) << 3)];
      bf16x8 a1 = *(const bf16x8*)&As[(rb << 6) + ((ch ^ (rb & 7)) << 3)];
      bf16x8 b0 = *(const bf16x8*)&Bs[(ca << 6) + ((ch ^ (ca & 7)) << 3)];
      bf16x8 b1 = *(const bf16x8*)&Bs[(cb << 6) + ((ch ^ (cb & 7)) << 3)];
      acc[0][0] = __builtin_amdgcn_mfma_f32_16x16x32_bf16(a0, b0, acc[0][0], 0, 0, 0);
      acc[0][1] = __builtin_amdgcn_mfma_f32_16x16x32_bf16(a0, b1, acc[0][1], 0, 0, 0);
      acc[1][0] = __builtin_amdgcn_mfma_f32_16x16x32_bf16(a1, b0, acc[1][0], 0, 0, 0);
      acc[1][1] = __builtin_amdgcn_mfma_f32_16x16x32_bf16(a1, b1, acc[1][1], 0, 0, 0);
    }
    __syncthreads();
  }
  int lrow = (l >> 4) << 2, lcol = l & 15;
  float* P = Pf + (size_t)s * M * N;
#pragma unroll
  for (int i = 0; i < 2; ++i)
#pragma unroll
    for (int j = 0; j < 2; ++j) {
      int c = col0 + wc + (j << 4) + lcol;
      int r0 = row0 + wr + (i << 4) + lrow;
#pragma unroll
      for (int rg = 0; rg < 4; ++rg)
        P[(size_t)(r0 + rg) * N + c] = acc[i][j][rg];
    }
}

// ---- non-split GEMM with fused epilogue; smem: 16640 B ----
__device__ void gemm_e_body(char* smem, int bid, const float* __restrict__ A,
                            const unsigned short* __restrict__ BT,
                            const int* __restrict__ permA, const float* __restrict__ valsA,
                            const float* __restrict__ dinv, int dm,
                            float* __restrict__ Cf, unsigned short* __restrict__ CbT,
                            int M, int N, int K, int nbx) {
  unsigned short* As = (unsigned short*)smem;
  unsigned short* Bs = (unsigned short*)(smem + 8192);
  int tid = threadIdx.x;
  int by = bid / nbx, bx = bid % nbx;
  int row0 = by << 6, col0 = bx << 6;
  int l = tid & 63, wv = tid >> 6;
  int wr = (wv >> 1) << 5, wc = (wv & 1) << 5;
  f32x4 acc[2][2] = {};
  for (int k0 = 0; k0 < K; k0 += 64) {
#pragma unroll
    for (int it = 0; it < 2; ++it) {
      int idx = (it << 8) + tid;
      int r = idx >> 3, c8 = idx & 7;
      int sw = c8 ^ (r & 7);
      int row = row0 + r;
      int srow = permA ? permA[row] : row;
      float vs = valsA ? valsA[row] : 1.f;
      const float* Af = A + (size_t)srow * K + k0 + (c8 << 3);
      float4 f0 = *(const float4*)Af;
      float4 f1 = *(const float4*)(Af + 4);
      uint4 u;
      u.x = (unsigned)f2bf(f0.x * vs) | ((unsigned)f2bf(f0.y * vs) << 16);
      u.y = (unsigned)f2bf(f0.z * vs) | ((unsigned)f2bf(f0.w * vs) << 16);
      u.z = (unsigned)f2bf(f1.x * vs) | ((unsigned)f2bf(f1.y * vs) << 16);
      u.w = (unsigned)f2bf(f1.z * vs) | ((unsigned)f2bf(f1.w * vs) << 16);
      ((uint4*)As)[(r << 3) + sw] = u;
      ((uint4*)Bs)[(r << 3) + sw] =
          *(const uint4*)(BT + (size_t)(col0 + r) * K + k0 + (c8 << 3));
    }
    __syncthreads();
#pragma unroll
    for (int kk2 = 0; kk2 < 2; ++kk2) {
      int ch = (kk2 << 2) + (l >> 4);
      int ra = wr + (l & 15), rb = ra + 16;
      int ca = wc + (l & 15), cb = ca + 16;
      bf16x8 a0 = *(const bf16x8*)&As[(ra << 6) + ((ch ^ (ra & 7)) << 3)];
      bf16x8 a1 = *(const bf16x8*)&As[(rb << 6) + ((ch ^ (rb & 7)) << 3)];
      bf16x8 b0 = *(const bf16x8*)&Bs[(ca << 6) + ((ch ^ (ca & 7)) << 3)];
      bf16x8 b1 = *(const bf16x8*)&Bs[(cb << 6) + ((ch ^ (cb & 7)) << 3)];
      acc[0][0] = __builtin_amdgcn_mfma_f32_16x16x32_bf16(a0, b0, acc[0][0], 0, 0, 0);
      acc[0][1] = __builtin_amdgcn_mfma_f32_16x16x32_bf16(a0, b1, acc[0][1], 0, 0, 0);
      acc[1][0] = __builtin_amdgcn_mfma_f32_16x16x32_bf16(a1, b0, acc[1][0], 0, 0, 0);
      acc[1][1] = __builtin_amdgcn_mfma_f32_16x16x32_bf16(a1, b1, acc[1][1], 0, 0, 0);
    }
    __syncthreads();
  }
  int lrow = (l >> 4) << 2, lcol = l & 15;
  float* tf = (float*)smem;
#pragma unroll
  for (int i = 0; i < 2; ++i)
#pragma unroll
    for (int j = 0; j < 2; ++j) {
      int lc = wc + (j << 4) + lcol;
      int lr0 = wr + (i << 4) + lrow;
      int c = col0 + lc;
#pragma unroll
      for (int rg = 0; rg < 4; ++rg) {
        int lr = lr0 + rg;
        int r = row0 + lr;
        float dv = (dm == 1) ? dinv[r] : 1.f;
        float v = acc[i][j][rg] * dv;
        if (Cf) Cf[(size_t)r * N + c] = v;
        if (CbT) tf[lr * 65 + lc] = v;
      }
    }
  if (CbT) {
    __syncthreads();
    for (int it = 0; it < 16; ++it) {
      int idx = (it << 8) + tid;
      int rr = idx >> 6, cc = idx & 63;
      CbT[(size_t)(col0 + rr) * M + row0 + cc] = f2bf(tf[cc * 65 + rr]);
    }
  }
}

__global__ __launch_bounds__(256) void gemm_e_k(const float* A, const unsigned short* BT,
                                                const int* permA, const float* valsA,
                                                const float* dinv, int dm, float* Cf,
                                                unsigned short* CbT, int M, int N, int K,
                                                int nbx) {
  __shared__ char smem[16640];
  gemm_e_body(smem, blockIdx.x, A, BT, permA, valsA, dinv, dm, Cf, CbT, M, N, K, nbx);
}

// ---- W2 partials: W2p[s] = A1[p2,:]@A1[:,p2] slice (plain stores, no atomics) ----
// degsum2 row-sum atomics retained (small, integer-exact, order-free).
__device__ void mm_w2_body(char* smem, int bid, const unsigned short* __restrict__ Wb,
                           const unsigned short* __restrict__ WbT,
                           const int* __restrict__ perm2, float* __restrict__ W2p,
                           float* __restrict__ degsum2) {
  unsigned short* As = (unsigned short*)smem;
  unsigned short* Bs = (unsigned short*)(smem + 8192);
  int* pr = (int*)(smem + 16384);
  int* pc = pr + 64;
  int tid = threadIdx.x;
  int s = bid >> 8;
  int t2d = bid & 255;
  int bx = t2d & 15, by = t2d >> 4;
  int row0 = by << 6, col0 = bx << 6;
  int ks = s * 512, ke = ks + 512;
  if (tid < 64) pr[tid] = perm2[row0 + tid];
  else if (tid < 128) pc[tid - 64] = perm2[col0 + tid - 128 + 64];
  __syncthreads();
  int l = tid & 63, wv = tid >> 6;
  int wr = (wv >> 1) << 5, wc = (wv & 1) << 5;
  f32x4 acc[2][2] = {};
  for (int k0 = ks; k0 < ke; k0 += 64) {
#pragma unroll
    for (int it = 0; it < 2; ++it) {
      int idx = (it << 8) + tid;
      int r = idx >> 3, c8 = idx & 7;
      int sw = c8 ^ (r & 7);
      ((uint4*)As)[(r << 3) + sw] =
          *(const uint4*)(Wb + (size_t)pr[r] * 2048 + k0 + (c8 << 3));
      ((uint4*)Bs)[(r << 3) + sw] =
          *(const uint4*)(WbT + (size_t)pc[r] * 2048 + k0 + (c8 << 3));
    }
    __syncthreads();
#pragma unroll
    for (int kk2 = 0; kk2 < 2; ++kk2) {
      int ch = (kk2 << 2) + (l >> 4);
      int ra = wr + (l & 15), rb = ra + 16;
      int ca = wc + (l & 15), cb = ca + 16;
      bf16x8 a0 = *(const bf16x8*)&As[(ra << 6) + ((ch ^ (ra & 7)) << 3)];
      bf16x8 a1 = *(const bf16x8*)&As[(rb << 6) + ((ch ^ (rb & 7)) << 3)];
      bf16x8 b0 = *(const bf16x8*)&Bs[(ca << 6) + ((ch ^ (ca & 7)) << 3)];
      bf16x8 b1 = *(const bf16x8*)&Bs[(cb << 6) + ((ch ^ (cb & 7)) << 3)];
      acc[0][0] = __builtin_amdgcn_mfma_f32_16x16x32_bf16(a0, b0, acc[0][0], 0, 0, 0);
      acc[0][1] = __builtin_amdgcn_mfma_f32_16x16x32_bf16(a0, b1, acc[0][1], 0, 0, 0);
      acc[1][0] = __builtin_amdgcn_mfma_f32_16x16x32_bf16(a1, b0, acc[1][0], 0, 0, 0);
      acc[1][1] = __builtin_amdgcn_mfma_f32_16x16x32_bf16(a1, b1, acc[1][1], 0, 0, 0);
    }
    __syncthreads();
  }
  int lrow = (l >> 4) << 2, lcol = l & 15;
  float* P = W2p + (size_t)s * P2K * P2K;
#pragma unroll
  for (int i = 0; i < 2; ++i)
#pragma unroll
    for (int j = 0; j < 2; ++j) {
      int c = col0 + wc + (j << 4) + lcol;
      int r0 = row0 + wr + (i << 4) + lrow;
#pragma unroll
      for (int rg = 0; rg < 4; ++rg)
        P[(size_t)(r0 + rg) * 1024 + c] = acc[i][j][rg];
    }
#pragma unroll
  for (int i = 0; i < 2; ++i)
#pragma unroll
    for (int rg = 0; rg < 4; ++rg) {
      float rs = acc[i][0][rg] + acc[i][1][rg];
#pragma unroll
      for (int o = 1; o < 16; o <<= 1) rs += __shfl_xor(rs, o, 64);
      if ((l & 15) == 0) {
        int r = row0 + wr + (i << 4) + lrow + rg;
        atomicAdd(&degsum2[r], rs);
      }
    }
}

__global__ __launch_bounds__(256) void fused_w2_g2a(
    const unsigned short* Wb, const unsigned short* WbT, const int* perm2, float* W2p,
    float* degsum2, const float* x1b, const unsigned short* t2T, const float* vals2,
    unsigned short* SAbT) {
  __shared__ char smem[16896];
  if (blockIdx.x < 1024) mm_w2_body(smem, blockIdx.x, Wb, WbT, perm2, W2p, degsum2);
  else gemm_e_body(smem, blockIdx.x - 1024, x1b, t2T, perm2, vals2, nullptr, 0,
                   nullptr, SAbT, 1024, 512, 512, 8);
}

// W2p slices -> W2Tb = ((W2 diag-zeroed + I) rows scaled by dinv2)^T bf16; emit dinv2
__global__ __launch_bounds__(256) void w2T(const float* __restrict__ W2p,
                                           const float* __restrict__ degsum2,
                                           unsigned short* __restrict__ W2Tb,
                                           float* __restrict__ dinv2v) {
  __shared__ float t[64][65];
  __shared__ float ds[64];
  const size_t SL = (size_t)P2K * P2K;
  int bx = blockIdx.x & 15, by = blockIdx.x >> 4;
  int r0 = by << 6, c0 = bx << 6;
  if (threadIdx.x < 64) {
    int r = r0 + threadIdx.x;
    float diag = 0.f;
#pragma unroll
    for (int s = 0; s < SPLITS; ++s) diag += W2p[s * SL + (size_t)r * 1024 + r];
    float dg = degsum2[r] - diag;  // exclude diag (integers: exact)
    float dv = rsqrtf(dg + 1.f);
    ds[threadIdx.x] = dv;
    if (bx == 0) dinv2v[r] = dv;
  }
  for (int it = 0; it < 16; ++it) {
    int idx = (it << 8) + threadIdx.x;
    int r = idx >> 6, c = idx & 63;
    size_t o = (size_t)(r0 + r) * 1024 + c0 + c;
    float v = 0.f;
#pragma unroll
    for (int s = 0; s < SPLITS; ++s) v += W2p[s * SL + o];
    if (r0 + r == c0 + c) v = 1.f;  // A2 = W2_diagzeroed + I
    t[r][c] = v;
  }
  __syncthreads();
  for (int it = 0; it < 16; ++it) {
    int idx = (it << 8) + threadIdx.x;
    int rr = idx >> 6, cc = idx & 63;
    W2Tb[(size_t)(c0 + rr) * 1024 + r0 + cc] = f2bf(t[cc][rr] * ds[cc]);
  }
}

// reduce + GCN epilogue (agg includes +I); optional scatter-add
__global__ __launch_bounds__(256) void epi_red1(const float* __restrict__ Pf,
                                                const float* __restrict__ dinv,
                                                const float* __restrict__ bias,
                                                const int* __restrict__ permS,
                                                float* __restrict__ scatterDst,
                                                float* __restrict__ outp, int M, int N) {
  int g = blockIdx.x * 256 + threadIdx.x;
  size_t base = (size_t)g * 4;
  size_t MN = (size_t)M * N;
  if (base >= MN) return;
  int r = (int)(base / N), c = (int)(base % N);
  float4 a = *(const float4*)&Pf[base];
#pragma unroll
  for (int s = 1; s < SPLITS; ++s) {
    float4 p = *(const float4*)&Pf[s * MN + base];
    a.x += p.x; a.y += p.y; a.z += p.z; a.w += p.w;
  }
  float dv = dinv[r];
  float4 bb = *(const float4*)&bias[c];
  float4 o;
  o.x = fmaxf(dv * a.x + bb.x, 0.f);
  o.y = fmaxf(dv * a.y + bb.y, 0.f);
  o.z = fmaxf(dv * a.z + bb.z, 0.f);
  o.w = fmaxf(dv * a.w + bb.w, 0.f);
  if (outp) *(float4*)&outp[base] = o;
  if (permS) {
    float4* d = (float4*)&scatterDst[(size_t)permS[r] * N + c];
    float4 cur = *d;
    cur.x += o.x; cur.y += o.y; cur.z += o.z; cur.w += o.w;
    *d = cur;
  }
}

// 4-slice reduce + relu + pool-2 score. M=2048, N=512. 2 rows/block.
__global__ __launch_bounds__(256) void epi_red1s(const float* __restrict__ Pf,
                                                 const float* __restrict__ dinv,
                                                 const float* __restrict__ bias,
                                                 const float* __restrict__ pvec,
                                                 float* __restrict__ sc,
                                                 float* __restrict__ outp) {
  __shared__ float shs[2][2][2];
  int li = threadIdx.x & 127;
  int lr = threadIdx.x >> 7;
  int r = blockIdx.x * 2 + lr;
  size_t base = (size_t)r * 512 + li * 4;
  const size_t MN = (size_t)2048 * 512;
  float4 a = *(const float4*)&Pf[base];
#pragma unroll
  for (int s = 1; s < SPLITS; ++s) {
    float4 p = *(const float4*)&Pf[s * MN + base];
    a.x += p.x; a.y += p.y; a.z += p.z; a.w += p.w;
  }
  float dv = dinv[r];
  float4 bb = *(const float4*)&bias[li * 4];
  float4 o;
  o.x = fmaxf(dv * a.x + bb.x, 0.f);
  o.y = fmaxf(dv * a.y + bb.y, 0.f);
  o.z = fmaxf(dv * a.z + bb.z, 0.f);
  o.w = fmaxf(dv * a.w + bb.w, 0.f);
  *(float4*)&outp[base] = o;
  float4 pv = *(const float4*)&pvec[li * 4];
  float s1 = pv.x * pv.x + pv.y * pv.y + pv.z * pv.z + pv.w * pv.w;
  float s2 = o.x * pv.x + o.y * pv.y + o.z * pv.z + o.w * pv.w;
#pragma unroll
  for (int t = 32; t > 0; t >>= 1) {
    s1 += __shfl_down(s1, t, 64);
    s2 += __shfl_down(s2, t, 64);
  }
  int wir = (threadIdx.x >> 6) & 1;
  if ((threadIdx.x & 63) == 0) { shs[lr][wir][0] = s1; shs[lr][wir][1] = s2; }
  __syncthreads();
  if ((threadIdx.x & 127) == 0) {
    float S1 = shs[lr][0][0] + shs[lr][1][0];
    float S2 = shs[lr][0][1] + shs[lr][1][1];
    sc[r] = tanhf(S2 / sqrtf(S1));
  }
}

// level-0 GCN epilogue + (optional) pool score. C=256: row == one wave.
template <int C, bool SCORE>
__global__ __launch_bounds__(256) void gcn_spmm4(const int* __restrict__ iptr,
                                                 const int* __restrict__ isrc,
                                                 const float* __restrict__ Z,
                                                 const float* __restrict__ dinv,
                                                 const float* __restrict__ bias,
                                                 const float* __restrict__ pvec,
                                                 float* __restrict__ sc,
                                                 float* __restrict__ outp) {
  constexpr int L = C / 4;
  int li = threadIdx.x % L;
  int i = blockIdx.x * (256 / L) + threadIdx.x / L;
  float4 acc = *(const float4*)(Z + (size_t)i * C + li * 4);
  int beg = iptr[i], end = iptr[i + 1];
  for (int e = beg; e < end; ++e) {
    float4 z = *(const float4*)(Z + (size_t)isrc[e] * C + li * 4);
    acc.x += z.x; acc.y += z.y; acc.z += z.z; acc.w += z.w;
  }
  float d = dinv[i];
  float4 bb = *(const float4*)(bias + li * 4);
  float4 o;
  o.x = fmaxf(d * acc.x + bb.x, 0.f);
  o.y = fmaxf(d * acc.y + bb.y, 0.f);
  o.z = fmaxf(d * acc.z + bb.z, 0.f);
  o.w = fmaxf(d * acc.w + bb.w, 0.f);
  *(float4*)(outp + (size_t)i * C + li * 4) = o;
  if (SCORE) {
    float4 pv = *(const float4*)(pvec + li * 4);
    float s1 = pv.x * pv.x + pv.y * pv.y + pv.z * pv.z + pv.w * pv.w;
    float s2 = o.x * pv.x + o.y * pv.y + o.z * pv.z + o.w * pv.w;
#pragma unroll
    for (int t = 32; t > 0; t >>= 1) {
      s1 += __shfl_down(s1, t, 64);
      s2 += __shfl_down(s2, t, 64);
    }
    if ((threadIdx.x & 63) == 0) sc[i] = tanhf(s2 / sqrtf(s1));
  }
}

// ---- top-k via radix select ----
__global__ __launch_bounds__(1024) void topk_select(const float* __restrict__ score,
                                                    int n, int k, int* __restrict__ perm,
                                                    float* __restrict__ vals,
                                                    int* __restrict__ rank) {
  __shared__ unsigned int keys[4096];
  __shared__ int hist[256];
  __shared__ int wsums[16];
  __shared__ unsigned int sh_prefix;
  __shared__ int sh_rem;
  int t = threadIdx.x;
  int m = n >> 10;
  for (int i = t; i < n; i += 1024) {
    unsigned int u = __float_as_uint(score[i]);
    keys[i] = u ^ ((unsigned int)((int)u >> 31) | 0x80000000u);
  }
  if (t == 0) { sh_prefix = 0u; sh_rem = k; }
  __syncthreads();
  for (int round = 0; round < 4; ++round) {
    int shift = 24 - (round << 3);
    if (t < 256) hist[t] = 0;
    __syncthreads();
    unsigned int prefix = sh_prefix;
    unsigned int maskhi = (round == 0) ? 0u : (0xFFFFFFFFu << (shift + 8));
    for (int i = t; i < n; i += 1024) {
      unsigned int kk = keys[i];
      if ((kk & maskhi) == prefix) atomicAdd(&hist[(kk >> shift) & 255], 1);
    }
    __syncthreads();
    if (t == 0) {
      int rem = sh_rem, acc = 0, b = 255;
      for (; b > 0; --b) {
        if (acc + hist[b] >= rem) break;
        acc += hist[b];
      }
      sh_rem = rem - acc;
      sh_prefix = prefix | ((unsigned int)b << shift);
    }
    __syncthreads();
  }
  unsigned int thr = sh_prefix;
  int need = sh_rem;
  int base = t * m;
  int f[4];
  int cnt = 0;
#pragma unroll
  for (int j = 0; j < 4; ++j) {
    f[j] = 0;
    if (j < m) { f[j] = (keys[base + j] == thr) ? 1 : 0; cnt += f[j]; }
  }
  int ex = blockScanExclusive(cnt, wsums);
  int sel[4];
  int scnt = 0;
#pragma unroll
  for (int j = 0; j < 4; ++j) {
    sel[j] = 0;
    if (j < m) {
      unsigned int kk = keys[base + j];
      sel[j] = (kk > thr) || (kk == thr && ex < need);
      ex += f[j];
      scnt += sel[j];
    }
  }
  int pos = blockScanExclusive(scnt, wsums);
#pragma unroll
  for (int j = 0; j < 4; ++j) {
    if (j < m) {
      int i = base + j;
      if (sel[j]) {
        unsigned int kk = keys[i];
        unsigned int u = (kk & 0x80000000u) ? (kk ^ 0x80000000u) : ~kk;
        perm[pos] = i;
        vals[pos] = __uint_as_float(u);
        rank[i] = pos;
        pos++;
      } else {
        rank[i] = -1;
      }
    }
  }
}

// A1[a,b] = W1+I (bf16, integer-exact, diag=1) + dinv1; wave-parallel
__global__ __launch_bounds__(256) void build_W1(const int* __restrict__ optr,
                                                const int* __restrict__ odst,
                                                const int* __restrict__ perm1,
                                                const int* __restrict__ rank1,
                                                unsigned short* __restrict__ W1b,
                                                float* __restrict__ dinv1) {
  __shared__ float row[2048];
  int a = blockIdx.x;
  int pa = perm1[a];
  for (int i = threadIdx.x; i < 2048; i += 256) row[i] = 0.f;
  __syncthreads();
  int kbeg = optr[pa], kend = optr[pa + 1];
  int nk = kend - kbeg + 1;
  int wv = threadIdx.x >> 6, lane = threadIdx.x & 63;
  for (int kidx = wv; kidx < nk; kidx += 4) {
    int k = (kidx == 0) ? pa : odst[kbeg + kidx - 1];
    int jbeg = optr[k], jend = optr[k + 1];
    for (int jj = jbeg - 1 + lane; jj < jend; jj += 64) {
      int j = (jj < jbeg) ? k : odst[jj];
      int rb = rank1[j];
      if (rb >= 0) atomicAdd(&row[rb], 1.0f);
    }
  }
  __syncthreads();
  float ssum = 0.f;
  for (int i = threadIdx.x; i < 2048; i += 256) {
    float v = row[i];
    W1b[(size_t)a * 2048 + i] = f2bf((i == a) ? 1.f : v);  // A1 = W1_offdiag + I
    ssum += (i == a) ? 0.f : v;
  }
  float t = blockReduceSum256(ssum);
  if (threadIdx.x == 0) dinv1[a] = rsqrtf(t + 1.0f);
}

__device__ void mean_cols_body(int c, const float* __restrict__ X, int R, int C,
                               float* __restrict__ outp) {
  float s = 0.f;
  for (int r = threadIdx.x; r < R; r += 256) s += X[(size_t)r * C + c];
  float t = blockReduceSum256(s);
  if (threadIdx.x == 0) outp[c] = t / (float)R;
}

__global__ __launch_bounds__(256) void fused_mean_up1a(
    const float* xb, float* meanOut, const float* x1b, const unsigned short* t3T,
    const float* dinv1, unsigned short* SAbT) {
  __shared__ char smem[16640];
  if (blockIdx.x < 512) mean_cols_body(blockIdx.x, xb, 1024, 512, meanOut);
  else gemm_e_body(smem, blockIdx.x - 512, x1b, t3T, nullptr, nullptr, dinv1, 1,
                   nullptr, SAbT, 2048, 256, 512, 4);
}

// ---------------- launcher ----------------
extern "C" void kernel_launch(void* const* d_in, const int* in_sizes, int n_in,
                              void* d_out, int out_size, void* d_ws, size_t ws_size,
                              hipStream_t stream) {
  const float* x      = (const float*)d_in[0];
  const int*   eidx   = (const int*)d_in[1];
  const float* theta0 = (const float*)d_in[2];
  const float* b0     = (const float*)d_in[3];
  const float* theta1 = (const float*)d_in[4];
  const float* b1     = (const float*)d_in[5];
  const float* theta2 = (const float*)d_in[6];
  const float* b2     = (const float*)d_in[7];
  const float* theta3 = (const float*)d_in[8];
  const float* b3     = (const float*)d_in[9];
  const float* theta4 = (const float*)d_in[10];
  const float* b4     = (const float*)d_in[11];
  const float* p1     = (const float*)d_in[12];
  const float* p2     = (const float*)d_in[13];
  const int E = in_sizes[1] / 2;
  const int* src = eidx;
  const int* dst = eidx + E;
  float* out = (float*)d_out;

  char* wsb = (char*)d_ws;
  size_t off = 0;
  auto alloc = [&](size_t bytes) -> void* {
    void* p = wsb + off;
    off = (off + bytes + 255) & ~(size_t)255;
    return p;
  };
  // zero-init block: cnt4 | degsum2  (one small memset; W2f no longer exists)
  char* zblock = (char*)alloc((size_t)4 * N0 * 4 + P2K * 4);
  int* cnt4 = (int*)zblock;
  float* degsum2 = (float*)(zblock + (size_t)4 * N0 * 4);
  size_t zbytes = (size_t)4 * N0 * 4 + P2K * 4;

  int* optr  = (int*)alloc((N0 + 1) * 4);
  int* iptr  = (int*)alloc((N0 + 1) * 4);
  int* odst  = (int*)alloc((size_t)E * 4);
  int* isrc  = (int*)alloc((size_t)E * 4);
  int* perm1 = (int*)alloc(P1K * 4);
  int* rank1 = (int*)alloc(N0 * 4);
  int* perm2 = (int*)alloc(P2K * 4);
  int* rank2 = (int*)alloc(P1K * 4);
  float* dinv0 = (float*)alloc(N0 * 4);
  float* dinv1 = (float*)alloc(P1K * 4);
  float* dinv2v = (float*)alloc(P2K * 4);
  float* vals1 = (float*)alloc(P1K * 4);
  float* vals2 = (float*)alloc(P2K * 4);
  float* score = (float*)alloc(N0 * 4);
  float* x0  = (float*)alloc((size_t)N0 * 256 * 4);
  float* x1b = (float*)alloc((size_t)P1K * 512 * 4);
  float* xb  = (float*)alloc((size_t)P2K * 512 * 4);
  float* SA  = (float*)alloc((size_t)P1K * 512 * 4);        // Z scratch fp32
  float* Pf  = (float*)alloc((size_t)SPLITS * 1048576 * 4); // split-K partials (16 MB)
  unsigned short* W1b  = (unsigned short*)alloc((size_t)P1K * P1K * 2);
  unsigned short* W1bT = (unsigned short*)alloc((size_t)P1K * P1K * 2);
  unsigned short* W2Tb = (unsigned short*)alloc((size_t)P2K * P2K * 2);
  unsigned short* SAbT = (unsigned short*)alloc((size_t)524288 * 2);
  unsigned short* ZhT  = (unsigned short*)alloc((size_t)512 * 2048 * 2);
  unsigned short* ZlT  = (unsigned short*)alloc((size_t)512 * 2048 * 2);
  unsigned short* t0hT = (unsigned short*)alloc((size_t)256 * 128 * 2);
  unsigned short* t0lT = (unsigned short*)alloc((size_t)256 * 128 * 2);
  unsigned short* t1hT = (unsigned short*)alloc((size_t)512 * 256 * 2);
  unsigned short* t1lT = (unsigned short*)alloc((size_t)512 * 256 * 2);
  unsigned short* t2T  = (unsigned short*)alloc((size_t)512 * 512 * 2);
  unsigned short* t3T  = (unsigned short*)alloc((size_t)256 * 512 * 2);
  unsigned short* t4T  = (unsigned short*)alloc((size_t)128 * 256 * 2);
  (void)ws_size; (void)n_in; (void)out_size;

  int* co = cnt4;
  int* ci = cnt4 + N0;
  int* fo = cnt4 + 2 * N0;
  int* fi = cnt4 + 3 * N0;

  // --- graph build (count_edges || weight transposes) ---
  hipMemsetAsync(zblock, 0, zbytes, stream);
  fused_ce_conv<<<512 + 2304, 256, 0, stream>>>(src, dst, co, ci, E, theta0, theta1,
                                                theta2, theta3, theta4, t0hT, t0lT,
                                                t1hT, t1lT, t2T, t3T, t4T);
  exscan_dual<<<2, 1024, 0, stream>>>(co, ci, optr, iptr, dinv0);
  // fill_edges || gcn0 feature GEMM
  fused_fill_g3<<<512 + 256, 256, 0, stream>>>(src, dst, optr, iptr, fo, fi, odst, isrc,
                                               E, x, t0hT, t0lT, dinv0, SA);
  gcn_spmm4<256, true><<<1024, 256, 0, stream>>>(iptr, isrc, SA, dinv0, b0, p1, score, x0);

  // --- pool 1 ---
  topk_select<<<1, 1024, 0, stream>>>(score, 4096, 2048, perm1, vals1, rank1);
  build_W1<<<2048, 256, 0, stream>>>(optr, odst, perm1, rank1, W1b, dinv1);
  // A1 transpose || gcn1 feature GEMM
  fused_tr_g3<<<1024 + 256, 256, 0, stream>>>(W1b, W1bT, x0, t1hT, t1lT, perm1, vals1,
                                              dinv1, ZhT, ZlT);

  // --- gcn1 aggregation: A1^T (Zh+Zl) (+I folded) + pool-2 scores ---
  gemm_skd<<<256 * SPLITS, 256, 0, stream>>>(W1bT, ZhT, ZlT, Pf, 2048, 512, 2048, 8, 256);
  epi_red1s<<<1024, 256, 0, stream>>>(Pf, dinv1, b1, p2, score, x1b);

  // --- pool 2 ---
  topk_select<<<1, 1024, 0, stream>>>(score, 2048, 1024, perm2, vals2, rank2);
  // W2 partial slices (plain stores, into Pf) || gcn2 feature GEMM
  fused_w2_g2a<<<1024 + 128, 256, 0, stream>>>(W1b, W1bT, perm2, Pf, degsum2, x1b, t2T,
                                               vals2, SAbT);
  w2T<<<256, 256, 0, stream>>>(Pf, degsum2, W2Tb, dinv2v);

  // --- gcn2 aggregation: (A2 dinv2)^T Y; epilogue scatters into x1b ---
  gemm_sk<<<128 * SPLITS, 256, 0, stream>>>(W2Tb, SAbT, Pf, 1024, 512, 1024, 8, 128);
  epi_red1<<<1024 * 512 / 1024, 256, 0, stream>>>(Pf, dinv2v, b2, perm2, x1b, xb,
                                                  1024, 512);
  // summary mean || up1 feature GEMM
  fused_mean_up1a<<<512 + 128, 256, 0, stream>>>(xb, out + 524288, x1b, t3T, dinv1, SAbT);

  // --- up block 1: A1^T Z3 (+I folded); epilogue scatters into x0 ---
  gemm_sk<<<128 * SPLITS, 256, 0, stream>>>(W1bT, SAbT, Pf, 2048, 256, 2048, 4, 128);
  epi_red1<<<2048 * 256 / 1024, 256, 0, stream>>>(Pf, dinv1, b3, perm1, x0, nullptr,
                                                  2048, 256);

  // --- up block 0: feature GEMM + fp32 sparse agg -> out ---
  gemm_e_k<<<128, 256, 0, stream>>>(x0, t4T, nullptr, nullptr, dinv0, 1, SA, nullptr,
                                    4096, 128, 256, 2);
  gcn_spmm4<128, false><<<512, 256, 0, stream>>>(iptr, isrc, SA, dinv0, b4, nullptr,
                                                 nullptr, out);
}